// Round 3
// baseline (3827.027 us; speedup 1.0000x reference)
//
#include <hip/hip_runtime.h>

#define F_IN 128

// ---------------- degree / dinv ----------------

__global__ void zero_int_kernel(int* __restrict__ p, int n) {
    int i = blockIdx.x * blockDim.x + threadIdx.x;
    if (i < n) p[i] = 0;
}

__global__ void deg_kernel(const int* __restrict__ dst, int* __restrict__ deg, int E) {
    int i = blockIdx.x * blockDim.x + threadIdx.x;
    if (i < E) atomicAdd(&deg[dst[i]], 1);
}

__global__ void dinv_kernel(const int* __restrict__ deg, float* __restrict__ dinv, int N) {
    int i = blockIdx.x * blockDim.x + threadIdx.x;
    if (i < N) dinv[i] = rsqrtf((float)(deg[i] + 1));  // +1 self-loop; always > 0
}

// ---------------- GEMM + dinv scaling ----------------
// h = X @ W  (X: [N,128], W: [128,FO]); g = dinv[row]*h written to both g and acc.
// Block: 256 threads handles ROWS = 1024/FO rows; each thread computes 4 rows x 1 col.
// W staged in K-tiles of 64 rows -> max LDS = 32KB (Ws) + 4.2/8.4KB (Xs) < 64KB.

template<int FO>
__global__ __launch_bounds__(256) void gemm_scale_kernel(
    const float* __restrict__ X, const float* __restrict__ W,
    const float* __restrict__ dinv, float* __restrict__ g,
    float* __restrict__ acc, int N)
{
    constexpr int ROWS = 1024 / FO;   // 8 (FO=128) or 16 (FO=64)
    constexpr int TR   = 256 / FO;    // 2 or 4 row-groups per thread sweep
    constexpr int KT   = 64;          // K tile
    __shared__ float Ws[KT * FO];           // 32KB or 16KB
    __shared__ float Xs[ROWS][F_IN + 4];    // +4 pad keeps 16B align, breaks aliasing

    int row0 = blockIdx.x * ROWS;
    // stage X rows (ROWS x 128 floats), vectorized
    for (int i = threadIdx.x; i < ROWS * (F_IN / 4); i += 256) {
        int r  = i >> 5;          // /32
        int k4 = i & 31;
        int gr = row0 + r;
        float4 v = make_float4(0.f, 0.f, 0.f, 0.f);
        if (gr < N) v = ((const float4*)(X + (size_t)gr * F_IN))[k4];
        ((float4*)(&Xs[r][0]))[k4] = v;
    }

    int c  = threadIdx.x % FO;
    int rh = threadIdx.x / FO;    // 0..TR-1

    float s[4] = {0.f, 0.f, 0.f, 0.f};
    for (int kt = 0; kt < F_IN; kt += KT) {
        __syncthreads();   // first iter: covers Xs staging; later: Ws reuse
        for (int i = threadIdx.x; i < (KT * FO) / 4; i += 256)
            ((float4*)Ws)[i] = ((const float4*)(W + (size_t)kt * FO))[i];
        __syncthreads();
        #pragma unroll
        for (int k = 0; k < KT; ++k) {
            float w = Ws[k * FO + c];
            #pragma unroll
            for (int j = 0; j < 4; ++j)
                s[j] = fmaf(Xs[rh + TR * j][kt + k], w, s[j]);
        }
    }

    #pragma unroll
    for (int j = 0; j < 4; ++j) {
        int gr = row0 + rh + TR * j;
        if (gr < N) {
            float gv = dinv[gr] * s[j];
            size_t o = (size_t)gr * FO + c;
            g[o]   = gv;
            acc[o] = gv;   // self-loop init
        }
    }
}

// ---------------- edge scatter: acc[dst] += g[src] ----------------

template<int FO>
__global__ __launch_bounds__(256) void scatter_add_kernel(
    const int* __restrict__ src, const int* __restrict__ dst,
    const float* __restrict__ g, float* __restrict__ acc, int E)
{
    constexpr int CH  = FO / 4;               // float4 chunks per edge: 32 or 16
    constexpr int LOG = (CH == 32) ? 5 : 4;
    int gid = blockIdx.x * 256 + threadIdx.x;
    if (gid >= E * CH) return;                // <= 25.6M, fits int
    int e = gid >> LOG;
    int c = gid & (CH - 1);
    int s = src[e];
    int d = dst[e];
    const float4 gv = *(const float4*)(g + (size_t)s * FO + (size_t)c * 4);
    float* ap = acc + (size_t)d * FO + (size_t)c * 4;
    atomicAdd(ap + 0, gv.x);
    atomicAdd(ap + 1, gv.y);
    atomicAdd(ap + 2, gv.z);
    atomicAdd(ap + 3, gv.w);
}

// ---------------- finalize: out = dinv*acc + b (, relu) ----------------

template<int FO, bool RELU>
__global__ __launch_bounds__(256) void finalize_kernel(
    const float* __restrict__ acc, float* __restrict__ out,
    const float* __restrict__ dinv, const float* __restrict__ b, int N)
{
    int idx = blockIdx.x * 256 + threadIdx.x;
    if (idx >= N * FO) return;
    int n = idx / FO;   // FO is pow2 -> shift
    int c = idx % FO;
    float v = fmaf(dinv[n], acc[idx], b[c]);
    if (RELU) v = fmaxf(v, 0.f);
    out[idx] = v;
}

// ---------------- launch ----------------

extern "C" void kernel_launch(void* const* d_in, const int* in_sizes, int n_in,
                              void* d_out, int out_size, void* d_ws, size_t ws_size,
                              hipStream_t stream) {
    const float* x  = (const float*)d_in[0];
    const int*   ei = (const int*)d_in[1];    // harness passes integer inputs as int32
    const float* W0 = (const float*)d_in[2];
    const float* b0 = (const float*)d_in[3];
    const float* W1 = (const float*)d_in[4];
    const float* b1 = (const float*)d_in[5];
    const float* W2 = (const float*)d_in[6];
    const float* b2 = (const float*)d_in[7];
    float* out = (float*)d_out;

    const int N = in_sizes[0] / F_IN;
    const int E = in_sizes[1] / 2;
    const int* src = ei;
    const int* dst = ei + E;

    char* ws = (char*)d_ws;
    float* bufA = (float*)ws;                                   // N*128 f32 (g scratch)
    float* bufB = (float*)(ws + (size_t)N * 128 * 4);           // N*128 f32 (features/acc)
    float* dinv = (float*)(ws + (size_t)N * 128 * 4 * 2);       // N f32
    int*   deg  = (int*)  (ws + (size_t)N * 128 * 4 * 2 + (size_t)N * 4); // N i32

    const int nb_nodes = (N + 255) / 256;
    const int nb_edges = (E + 255) / 256;

    zero_int_kernel<<<nb_nodes, 256, 0, stream>>>(deg, N);
    deg_kernel<<<nb_edges, 256, 0, stream>>>(dst, deg, E);
    dinv_kernel<<<nb_nodes, 256, 0, stream>>>(deg, dinv, N);

    // ---- layer 0: X = x -> g = bufA, acc = bufB ----
    {
        int blocks = (N + 7) / 8;
        gemm_scale_kernel<128><<<blocks, 256, 0, stream>>>(x, W0, dinv, bufA, bufB, N);
        int sb = (E * 32 + 255) / 256;
        scatter_add_kernel<128><<<sb, 256, 0, stream>>>(src, dst, bufA, bufB, E);
        int fb = (N * 128 + 255) / 256;
        finalize_kernel<128, true><<<fb, 256, 0, stream>>>(bufB, bufB, dinv, b0, N);
    }

    // ---- layer 1: X = bufB -> g = bufA, acc = bufB (in-place, rows disjoint) ----
    {
        int blocks = (N + 7) / 8;
        gemm_scale_kernel<128><<<blocks, 256, 0, stream>>>(bufB, W1, dinv, bufA, bufB, N);
        int sb = (E * 32 + 255) / 256;
        scatter_add_kernel<128><<<sb, 256, 0, stream>>>(src, dst, bufA, bufB, E);
        int fb = (N * 128 + 255) / 256;
        finalize_kernel<128, true><<<fb, 256, 0, stream>>>(bufB, bufB, dinv, b1, N);
    }

    // ---- layer 2: X = bufB -> g = bufA (as N*64), acc = d_out ----
    {
        int blocks = (N + 15) / 16;
        gemm_scale_kernel<64><<<blocks, 256, 0, stream>>>(bufB, W2, dinv, bufA, out, N);
        int sb = (E * 16 + 255) / 256;
        scatter_add_kernel<64><<<sb, 256, 0, stream>>>(src, dst, bufA, out, E);
        int fb = (N * 64 + 255) / 256;
        finalize_kernel<64, false><<<fb, 256, 0, stream>>>(out, out, dinv, b2, N);
    }
}

// Round 4
// 655.031 us; speedup vs baseline: 5.8425x; 5.8425x over previous
//
#include <hip/hip_runtime.h>

#define F_IN 128

// ---------------- degree / dinv ----------------

__global__ void zero_int_kernel(int* __restrict__ p, int n) {
    int i = blockIdx.x * blockDim.x + threadIdx.x;
    if (i < n) p[i] = 0;
}

__global__ void deg_kernel(const int* __restrict__ dst, int* __restrict__ deg, int E) {
    int i = blockIdx.x * blockDim.x + threadIdx.x;
    if (i < E) atomicAdd(&deg[dst[i]], 1);
}

__global__ void dinv_kernel(const int* __restrict__ deg, float* __restrict__ dinv, int N) {
    int i = blockIdx.x * blockDim.x + threadIdx.x;
    if (i < N) dinv[i] = rsqrtf((float)(deg[i] + 1));  // +1 self-loop; always > 0
}

// ---------------- CSR build: exclusive scan of deg + cursor placement ----------------

__global__ void scan_blocks(const int* __restrict__ deg, int* __restrict__ rp,
                            int* __restrict__ bsum, int N) {
    __shared__ int tmp[256];
    int t = threadIdx.x, i = blockIdx.x * 256 + t;
    int v = (i < N) ? deg[i] : 0;
    tmp[t] = v;
    __syncthreads();
    for (int off = 1; off < 256; off <<= 1) {
        int a = (t >= off) ? tmp[t - off] : 0;
        __syncthreads();
        tmp[t] += a;
        __syncthreads();
    }
    if (i < N) rp[i] = tmp[t] - v;                 // exclusive within block
    if (t == 255) bsum[blockIdx.x] = tmp[255];     // block total
}

__global__ void scan_bsum(int* __restrict__ bsum, int nb) {   // nb <= 256
    __shared__ int tmp[256];
    int t = threadIdx.x;
    int v = (t < nb) ? bsum[t] : 0;
    tmp[t] = v;
    __syncthreads();
    for (int off = 1; off < 256; off <<= 1) {
        int a = (t >= off) ? tmp[t - off] : 0;
        __syncthreads();
        tmp[t] += a;
        __syncthreads();
    }
    if (t < nb) bsum[t] = tmp[t] - v;              // exclusive block offsets
}

__global__ void add_offsets_kernel(int* __restrict__ rp, const int* __restrict__ bsum,
                                   int* __restrict__ cursor, int N) {
    int i = blockIdx.x * 256 + threadIdx.x;
    if (i < N) {
        int r = rp[i] + bsum[blockIdx.x];
        rp[i] = r;
        cursor[i] = r;
    }
}

__global__ void build_csr_kernel(const int* __restrict__ src, const int* __restrict__ dst,
                                 int* __restrict__ cursor, int* __restrict__ csr_src, int E) {
    int e = blockIdx.x * 256 + threadIdx.x;
    if (e < E) {
        int pos = atomicAdd(&cursor[dst[e]], 1);
        csr_src[pos] = src[e];
    }
}

// ---------------- GEMM + dinv scaling: g = dinv * (X @ W) ----------------

template<int FO>
__global__ __launch_bounds__(256) void gemm_scale_kernel(
    const float* __restrict__ X, const float* __restrict__ W,
    const float* __restrict__ dinv, float* __restrict__ g, int N)
{
    constexpr int ROWS = 1024 / FO;   // 8 (FO=128) or 16 (FO=64)
    constexpr int TR   = 256 / FO;    // 2 or 4 row-groups per thread sweep
    constexpr int KT   = 64;          // K tile
    __shared__ float Ws[KT * FO];           // 32KB or 16KB
    __shared__ float Xs[ROWS][F_IN + 4];

    int row0 = blockIdx.x * ROWS;
    for (int i = threadIdx.x; i < ROWS * (F_IN / 4); i += 256) {
        int r  = i >> 5;
        int k4 = i & 31;
        int gr = row0 + r;
        float4 v = make_float4(0.f, 0.f, 0.f, 0.f);
        if (gr < N) v = ((const float4*)(X + (size_t)gr * F_IN))[k4];
        ((float4*)(&Xs[r][0]))[k4] = v;
    }

    int c  = threadIdx.x % FO;
    int rh = threadIdx.x / FO;

    float s[4] = {0.f, 0.f, 0.f, 0.f};
    for (int kt = 0; kt < F_IN; kt += KT) {
        __syncthreads();
        for (int i = threadIdx.x; i < (KT * FO) / 4; i += 256)
            ((float4*)Ws)[i] = ((const float4*)(W + (size_t)kt * FO))[i];
        __syncthreads();
        #pragma unroll
        for (int k = 0; k < KT; ++k) {
            float w = Ws[k * FO + c];
            #pragma unroll
            for (int j = 0; j < 4; ++j)
                s[j] = fmaf(Xs[rh + TR * j][kt + k], w, s[j]);
        }
    }

    #pragma unroll
    for (int j = 0; j < 4; ++j) {
        int gr = row0 + rh + TR * j;
        if (gr < N)
            g[(size_t)gr * FO + c] = dinv[gr] * s[j];
    }
}

// ---------------- CSR aggregation + finalize ----------------
// One 64-lane wave per dst node. out[n] = dinv[n]*(g[n] + sum_{s in nbrs(n)} g[s]) + b  (, relu)

template<int FO, bool RELU>
__global__ __launch_bounds__(256) void aggregate_kernel(
    const float* __restrict__ g, const int* __restrict__ rp, const int* __restrict__ deg,
    const int* __restrict__ csr, const float* __restrict__ dinv,
    const float* __restrict__ bias, float* __restrict__ out, int N)
{
    constexpr int PER = FO / 64;   // 2 (FO=128) or 1 (FO=64)
    int gid  = blockIdx.x * 256 + threadIdx.x;
    int node = gid >> 6;
    int lane = gid & 63;
    if (node >= N) return;

    int start = rp[node];
    int dg    = deg[node];

    float a0, a1 = 0.f;
    if (PER == 2) {
        float2 sv = *(const float2*)(g + (size_t)node * FO + lane * 2);
        a0 = sv.x; a1 = sv.y;                      // self-loop term
    } else {
        a0 = g[(size_t)node * FO + lane];
    }

    int j = 0;
    for (; j + 1 < dg; j += 2) {                   // 2-way unroll for MLP
        int s0 = csr[start + j];
        int s1 = csr[start + j + 1];
        if (PER == 2) {
            float2 v0 = *(const float2*)(g + (size_t)s0 * FO + lane * 2);
            float2 v1 = *(const float2*)(g + (size_t)s1 * FO + lane * 2);
            a0 += v0.x + v1.x;
            a1 += v0.y + v1.y;
        } else {
            a0 += g[(size_t)s0 * FO + lane] + g[(size_t)s1 * FO + lane];
        }
    }
    if (j < dg) {
        int s0 = csr[start + j];
        if (PER == 2) {
            float2 v0 = *(const float2*)(g + (size_t)s0 * FO + lane * 2);
            a0 += v0.x; a1 += v0.y;
        } else {
            a0 += g[(size_t)s0 * FO + lane];
        }
    }

    float dn = dinv[node];
    if (PER == 2) {
        float2 bb = *(const float2*)(bias + lane * 2);
        float ox = fmaf(dn, a0, bb.x);
        float oy = fmaf(dn, a1, bb.y);
        if (RELU) { ox = fmaxf(ox, 0.f); oy = fmaxf(oy, 0.f); }
        *(float2*)(out + (size_t)node * FO + lane * 2) = make_float2(ox, oy);
    } else {
        float o = fmaf(dn, a0, bias[lane]);
        if (RELU) o = fmaxf(o, 0.f);
        out[(size_t)node * FO + lane] = o;
    }
}

// ---------------- launch ----------------

extern "C" void kernel_launch(void* const* d_in, const int* in_sizes, int n_in,
                              void* d_out, int out_size, void* d_ws, size_t ws_size,
                              hipStream_t stream) {
    const float* x  = (const float*)d_in[0];
    const int*   ei = (const int*)d_in[1];    // harness passes integer inputs as int32
    const float* W0 = (const float*)d_in[2];
    const float* b0 = (const float*)d_in[3];
    const float* W1 = (const float*)d_in[4];
    const float* b1 = (const float*)d_in[5];
    const float* W2 = (const float*)d_in[6];
    const float* b2 = (const float*)d_in[7];
    float* out = (float*)d_out;

    const int N = in_sizes[0] / F_IN;
    const int E = in_sizes[1] / 2;
    const int* src = ei;
    const int* dst = ei + E;

    char* ws = (char*)d_ws;
    size_t off = 0;
    float* bufA   = (float*)(ws + off); off += (size_t)N * 128 * 4;   // g scratch
    float* bufB   = (float*)(ws + off); off += (size_t)N * 128 * 4;   // features
    float* dinv   = (float*)(ws + off); off += (size_t)N * 4;
    int*   deg    = (int*)  (ws + off); off += (size_t)N * 4;
    int*   rowptr = (int*)  (ws + off); off += (size_t)N * 4;
    int*   cursor = (int*)  (ws + off); off += (size_t)N * 4;
    int*   bsum   = (int*)  (ws + off); off += 256 * 4;
    int*   csr    = (int*)  (ws + off); off += (size_t)E * 4;

    const int nb_nodes = (N + 255) / 256;   // 196 blocks (N=50000) -> fits scan_bsum
    const int nb_edges = (E + 255) / 256;
    const int nb_aggr  = (N * 64 + 255) / 256;

    // degree + dinv + CSR (built once, reused by all 3 layers)
    zero_int_kernel<<<nb_nodes, 256, 0, stream>>>(deg, N);
    deg_kernel<<<nb_edges, 256, 0, stream>>>(dst, deg, E);
    dinv_kernel<<<nb_nodes, 256, 0, stream>>>(deg, dinv, N);
    scan_blocks<<<nb_nodes, 256, 0, stream>>>(deg, rowptr, bsum, N);
    scan_bsum<<<1, 256, 0, stream>>>(bsum, nb_nodes);
    add_offsets_kernel<<<nb_nodes, 256, 0, stream>>>(rowptr, bsum, cursor, N);
    build_csr_kernel<<<nb_edges, 256, 0, stream>>>(src, dst, cursor, csr, E);

    // ---- layer 0: x -> bufA (g) -> bufB ----
    gemm_scale_kernel<128><<<(N + 7) / 8, 256, 0, stream>>>(x, W0, dinv, bufA, N);
    aggregate_kernel<128, true><<<nb_aggr, 256, 0, stream>>>(bufA, rowptr, deg, csr, dinv, b0, bufB, N);

    // ---- layer 1: bufB -> bufA (g) -> bufB ----
    gemm_scale_kernel<128><<<(N + 7) / 8, 256, 0, stream>>>(bufB, W1, dinv, bufA, N);
    aggregate_kernel<128, true><<<nb_aggr, 256, 0, stream>>>(bufA, rowptr, deg, csr, dinv, b1, bufB, N);

    // ---- layer 2: bufB -> bufA (g, N*64) -> out ----
    gemm_scale_kernel<64><<<(N + 15) / 16, 256, 0, stream>>>(bufB, W2, dinv, bufA, N);
    aggregate_kernel<64, false><<<nb_aggr, 256, 0, stream>>>(bufA, rowptr, deg, csr, dinv, b2, out, N);
}

// Round 5
// 394.091 us; speedup vs baseline: 9.7110x; 1.6621x over previous
//
#include <hip/hip_runtime.h>

#define F_IN 128

// ---------------- degree / dinv ----------------

__global__ void zero_int_kernel(int* __restrict__ p, int n) {
    int i = blockIdx.x * blockDim.x + threadIdx.x;
    if (i < n) p[i] = 0;
}

__global__ void deg_kernel(const int* __restrict__ dst, int* __restrict__ deg, int E) {
    int i = blockIdx.x * blockDim.x + threadIdx.x;
    if (i < E) atomicAdd(&deg[dst[i]], 1);
}

__global__ void dinv_kernel(const int* __restrict__ deg, float* __restrict__ dinv, int N) {
    int i = blockIdx.x * blockDim.x + threadIdx.x;
    if (i < N) dinv[i] = rsqrtf((float)(deg[i] + 1));  // +1 self-loop; always > 0
}

// ---------------- CSR build: exclusive scan of deg + cursor placement ----------------

__global__ void scan_blocks(const int* __restrict__ deg, int* __restrict__ rp,
                            int* __restrict__ bsum, int N) {
    __shared__ int tmp[256];
    int t = threadIdx.x, i = blockIdx.x * 256 + t;
    int v = (i < N) ? deg[i] : 0;
    tmp[t] = v;
    __syncthreads();
    for (int off = 1; off < 256; off <<= 1) {
        int a = (t >= off) ? tmp[t - off] : 0;
        __syncthreads();
        tmp[t] += a;
        __syncthreads();
    }
    if (i < N) rp[i] = tmp[t] - v;
    if (t == 255) bsum[blockIdx.x] = tmp[255];
}

__global__ void scan_bsum(int* __restrict__ bsum, int nb) {   // nb <= 256
    __shared__ int tmp[256];
    int t = threadIdx.x;
    int v = (t < nb) ? bsum[t] : 0;
    tmp[t] = v;
    __syncthreads();
    for (int off = 1; off < 256; off <<= 1) {
        int a = (t >= off) ? tmp[t - off] : 0;
        __syncthreads();
        tmp[t] += a;
        __syncthreads();
    }
    if (t < nb) bsum[t] = tmp[t] - v;
}

__global__ void add_offsets_kernel(int* __restrict__ rp, const int* __restrict__ bsum,
                                   int* __restrict__ cursor, int N) {
    int i = blockIdx.x * 256 + threadIdx.x;
    if (i < N) {
        int r = rp[i] + bsum[blockIdx.x];
        rp[i] = r;
        cursor[i] = r;
    }
}

__global__ void build_csr_kernel(const int* __restrict__ src, const int* __restrict__ dst,
                                 int* __restrict__ cursor, int* __restrict__ csr_src, int E) {
    int e = blockIdx.x * 256 + threadIdx.x;
    if (e < E) {
        int pos = atomicAdd(&cursor[dst[e]], 1);
        csr_src[pos] = src[e];
    }
}

// ---------------- GEMM: g = dinv * (X @ W), 8x8 register tile ----------------
// X: [N,128] row-major, W: [128,BN] row-major. Per-thread 8 rows x 8 cols.
// Xs staged TRANSPOSED [k][row] so row-dim b128 reads are contiguous.
// Lane map (trl,tcl)=(lane&7,lane>>3): 8 distinct X addrs + 8 distinct W addrs
// per wave -> 2-way bank aliasing only (free), rest broadcast.

template<int BM, int BN>
__global__ __launch_bounds__((BM / 8) * (BN / 8)) void gemm8x8_kernel(
    const float* __restrict__ X, const float* __restrict__ W,
    const float* __restrict__ dinv, float* __restrict__ g, int N)
{
    constexpr int K   = 128;
    constexpr int KT  = 32;
    constexpr int NT  = (BM / 8) * (BN / 8);
    constexpr int XS  = BM + 4;   // (BM+4)*4 % 16 == 0 -> b128-aligned rows
    constexpr int WS  = BN + 4;
    constexpr int TRG = BM / 8;

    __shared__ float Xs[KT * XS];
    __shared__ float Ws[KT * WS];

    const int tid  = threadIdx.x;
    const int lane = tid & 63;
    const int hi   = tid >> 6;
    const int trl  = lane & 7;
    const int tcl  = (lane >> 3) & 7;
    const int tr   = trl + 8 * (hi % (TRG / 8));
    const int tc   = tcl + 8 * (hi / (TRG / 8));

    const int row0 = blockIdx.x * BM;

    float acc[8][8];
    #pragma unroll
    for (int i = 0; i < 8; ++i)
        #pragma unroll
        for (int j = 0; j < 8; ++j) acc[i][j] = 0.f;

    for (int kt = 0; kt < K; kt += KT) {
        __syncthreads();
        // stage X transposed: global [row][kt+4f4+ii] -> Xs[(4f4+ii)][row]
        for (int idx = tid; idx < BM * (KT / 4); idx += NT) {
            int r  = idx / (KT / 4);
            int f4 = idx % (KT / 4);
            int gr = row0 + r;
            float4 v = make_float4(0.f, 0.f, 0.f, 0.f);
            if (gr < N) v = ((const float4*)(X + (size_t)gr * K + kt))[f4];
            Xs[(f4 * 4 + 0) * XS + r] = v.x;
            Xs[(f4 * 4 + 1) * XS + r] = v.y;
            Xs[(f4 * 4 + 2) * XS + r] = v.z;
            Xs[(f4 * 4 + 3) * XS + r] = v.w;
        }
        // stage W: [kt+kk][4j]
        for (int idx = tid; idx < KT * (BN / 4); idx += NT) {
            int kk = idx / (BN / 4);
            int j  = idx % (BN / 4);
            float4 v = ((const float4*)(W + (size_t)(kt + kk) * BN))[j];
            *(float4*)&Ws[kk * WS + 4 * j] = v;
        }
        __syncthreads();

        #pragma unroll 4
        for (int k = 0; k < KT; ++k) {
            float4 x0 = *(const float4*)&Xs[k * XS + tr * 8];
            float4 x1 = *(const float4*)&Xs[k * XS + tr * 8 + 4];
            float4 w0 = *(const float4*)&Ws[k * WS + tc * 8];
            float4 w1 = *(const float4*)&Ws[k * WS + tc * 8 + 4];
            float xr[8] = {x0.x, x0.y, x0.z, x0.w, x1.x, x1.y, x1.z, x1.w};
            float wr[8] = {w0.x, w0.y, w0.z, w0.w, w1.x, w1.y, w1.z, w1.w};
            #pragma unroll
            for (int i = 0; i < 8; ++i)
                #pragma unroll
                for (int j = 0; j < 8; ++j)
                    acc[i][j] = fmaf(xr[i], wr[j], acc[i][j]);
        }
    }

    #pragma unroll
    for (int i = 0; i < 8; ++i) {
        int gr = row0 + tr * 8 + i;
        if (gr < N) {
            float dn = dinv[gr];
            float* gp = g + (size_t)gr * BN + tc * 8;
            *(float4*)(gp + 0) = make_float4(dn * acc[i][0], dn * acc[i][1],
                                             dn * acc[i][2], dn * acc[i][3]);
            *(float4*)(gp + 4) = make_float4(dn * acc[i][4], dn * acc[i][5],
                                             dn * acc[i][6], dn * acc[i][7]);
        }
    }
}

// ---------------- CSR aggregation + finalize ----------------

template<int FO, bool RELU>
__global__ __launch_bounds__(256) void aggregate_kernel(
    const float* __restrict__ g, const int* __restrict__ rp, const int* __restrict__ deg,
    const int* __restrict__ csr, const float* __restrict__ dinv,
    const float* __restrict__ bias, float* __restrict__ out, int N)
{
    constexpr int PER = FO / 64;   // 2 (FO=128) or 1 (FO=64)
    int gid  = blockIdx.x * 256 + threadIdx.x;
    int node = gid >> 6;
    int lane = gid & 63;
    if (node >= N) return;

    int start = rp[node];
    int dg    = deg[node];

    float a0, a1 = 0.f;
    if (PER == 2) {
        float2 sv = *(const float2*)(g + (size_t)node * FO + lane * 2);
        a0 = sv.x; a1 = sv.y;
    } else {
        a0 = g[(size_t)node * FO + lane];
    }

    int j = 0;
    for (; j + 1 < dg; j += 2) {
        int s0 = csr[start + j];
        int s1 = csr[start + j + 1];
        if (PER == 2) {
            float2 v0 = *(const float2*)(g + (size_t)s0 * FO + lane * 2);
            float2 v1 = *(const float2*)(g + (size_t)s1 * FO + lane * 2);
            a0 += v0.x + v1.x;
            a1 += v0.y + v1.y;
        } else {
            a0 += g[(size_t)s0 * FO + lane] + g[(size_t)s1 * FO + lane];
        }
    }
    if (j < dg) {
        int s0 = csr[start + j];
        if (PER == 2) {
            float2 v0 = *(const float2*)(g + (size_t)s0 * FO + lane * 2);
            a0 += v0.x; a1 += v0.y;
        } else {
            a0 += g[(size_t)s0 * FO + lane];
        }
    }

    float dn = dinv[node];
    if (PER == 2) {
        float2 bb = *(const float2*)(bias + lane * 2);
        float ox = fmaf(dn, a0, bb.x);
        float oy = fmaf(dn, a1, bb.y);
        if (RELU) { ox = fmaxf(ox, 0.f); oy = fmaxf(oy, 0.f); }
        *(float2*)(out + (size_t)node * FO + lane * 2) = make_float2(ox, oy);
    } else {
        float o = fmaf(dn, a0, bias[lane]);
        if (RELU) o = fmaxf(o, 0.f);
        out[(size_t)node * FO + lane] = o;
    }
}

// ---------------- launch ----------------

extern "C" void kernel_launch(void* const* d_in, const int* in_sizes, int n_in,
                              void* d_out, int out_size, void* d_ws, size_t ws_size,
                              hipStream_t stream) {
    const float* x  = (const float*)d_in[0];
    const int*   ei = (const int*)d_in[1];    // harness passes integer inputs as int32
    const float* W0 = (const float*)d_in[2];
    const float* b0 = (const float*)d_in[3];
    const float* W1 = (const float*)d_in[4];
    const float* b1 = (const float*)d_in[5];
    const float* W2 = (const float*)d_in[6];
    const float* b2 = (const float*)d_in[7];
    float* out = (float*)d_out;

    const int N = in_sizes[0] / F_IN;
    const int E = in_sizes[1] / 2;
    const int* src = ei;
    const int* dst = ei + E;

    char* ws = (char*)d_ws;
    size_t off = 0;
    float* bufA   = (float*)(ws + off); off += (size_t)N * 128 * 4;   // g scratch
    float* bufB   = (float*)(ws + off); off += (size_t)N * 128 * 4;   // features
    float* dinv   = (float*)(ws + off); off += (size_t)N * 4;
    int*   deg    = (int*)  (ws + off); off += (size_t)N * 4;
    int*   rowptr = (int*)  (ws + off); off += (size_t)N * 4;
    int*   cursor = (int*)  (ws + off); off += (size_t)N * 4;
    int*   bsum   = (int*)  (ws + off); off += 256 * 4;
    int*   csr    = (int*)  (ws + off); off += (size_t)E * 4;

    const int nb_nodes = (N + 255) / 256;   // 196 blocks -> fits scan_bsum
    const int nb_edges = (E + 255) / 256;
    const int nb_aggr  = (N * 64 + 255) / 256;

    zero_int_kernel<<<nb_nodes, 256, 0, stream>>>(deg, N);
    deg_kernel<<<nb_edges, 256, 0, stream>>>(dst, deg, E);
    dinv_kernel<<<nb_nodes, 256, 0, stream>>>(deg, dinv, N);
    scan_blocks<<<nb_nodes, 256, 0, stream>>>(deg, rowptr, bsum, N);
    scan_bsum<<<1, 256, 0, stream>>>(bsum, nb_nodes);
    add_offsets_kernel<<<nb_nodes, 256, 0, stream>>>(rowptr, bsum, cursor, N);
    build_csr_kernel<<<nb_edges, 256, 0, stream>>>(src, dst, cursor, csr, E);

    // ---- layer 0: x -> bufA (g) -> bufB ----
    gemm8x8_kernel<64, 128><<<(N + 63) / 64, 128, 0, stream>>>(x, W0, dinv, bufA, N);
    aggregate_kernel<128, true><<<nb_aggr, 256, 0, stream>>>(bufA, rowptr, deg, csr, dinv, b0, bufB, N);

    // ---- layer 1: bufB -> bufA (g) -> bufB ----
    gemm8x8_kernel<64, 128><<<(N + 63) / 64, 128, 0, stream>>>(bufB, W1, dinv, bufA, N);
    aggregate_kernel<128, true><<<nb_aggr, 256, 0, stream>>>(bufA, rowptr, deg, csr, dinv, b1, bufB, N);

    // ---- layer 2: bufB -> bufA (g, N*64) -> out ----
    gemm8x8_kernel<128, 64><<<(N + 127) / 128, 128, 0, stream>>>(bufB, W2, dinv, bufA, N);
    aggregate_kernel<64, false><<<nb_aggr, 256, 0, stream>>>(bufA, rowptr, deg, csr, dinv, b2, out, N);
}

// Round 6
// 326.227 us; speedup vs baseline: 11.7312x; 1.2080x over previous
//
#include <hip/hip_runtime.h>
#include <hip/hip_fp16.h>

#define F_IN 128

struct alignas(16) half8 { __half2 h[4]; };

// ---------------- degree / dinv ----------------

__global__ void zero_int_kernel(int* __restrict__ p, int n) {
    int i = blockIdx.x * blockDim.x + threadIdx.x;
    if (i < n) p[i] = 0;
}

__global__ void deg_kernel(const int* __restrict__ dst, int* __restrict__ deg, int E) {
    int i = blockIdx.x * blockDim.x + threadIdx.x;
    if (i < E) atomicAdd(&deg[dst[i]], 1);
}

__global__ void dinv_kernel(const int* __restrict__ deg, float* __restrict__ dinv, int N) {
    int i = blockIdx.x * blockDim.x + threadIdx.x;
    if (i < N) dinv[i] = rsqrtf((float)(deg[i] + 1));  // +1 self-loop; always > 0
}

// ---------------- CSR build: exclusive scan of deg + cursor placement ----------------

__global__ void scan_blocks(const int* __restrict__ deg, int* __restrict__ rp,
                            int* __restrict__ bsum, int N) {
    __shared__ int tmp[256];
    int t = threadIdx.x, i = blockIdx.x * 256 + t;
    int v = (i < N) ? deg[i] : 0;
    tmp[t] = v;
    __syncthreads();
    for (int off = 1; off < 256; off <<= 1) {
        int a = (t >= off) ? tmp[t - off] : 0;
        __syncthreads();
        tmp[t] += a;
        __syncthreads();
    }
    if (i < N) rp[i] = tmp[t] - v;
    if (t == 255) bsum[blockIdx.x] = tmp[255];
}

__global__ void scan_bsum(int* __restrict__ bsum, int nb) {   // nb <= 256
    __shared__ int tmp[256];
    int t = threadIdx.x;
    int v = (t < nb) ? bsum[t] : 0;
    tmp[t] = v;
    __syncthreads();
    for (int off = 1; off < 256; off <<= 1) {
        int a = (t >= off) ? tmp[t - off] : 0;
        __syncthreads();
        tmp[t] += a;
        __syncthreads();
    }
    if (t < nb) bsum[t] = tmp[t] - v;
}

__global__ void add_offsets_kernel(int* __restrict__ rp, const int* __restrict__ bsum,
                                   int* __restrict__ cursor, int N) {
    int i = blockIdx.x * 256 + threadIdx.x;
    if (i < N) {
        int r = rp[i] + bsum[blockIdx.x];
        rp[i] = r;
        cursor[i] = r;
    }
}

__global__ void build_csr_kernel(const int* __restrict__ src, const int* __restrict__ dst,
                                 int* __restrict__ cursor, int* __restrict__ csr_src, int E) {
    int e = blockIdx.x * 256 + threadIdx.x;
    if (e < E) {
        int pos = atomicAdd(&cursor[dst[e]], 1);
        csr_src[pos] = src[e];
    }
}

// ---------------- GEMM: g = fp16(dinv * (X @ W)), 8x8 register tile ----------------

template<int BM, int BN>
__global__ __launch_bounds__((BM / 8) * (BN / 8)) void gemm8x8_kernel(
    const float* __restrict__ X, const float* __restrict__ W,
    const float* __restrict__ dinv, __half* __restrict__ g, int N)
{
    constexpr int K   = 128;
    constexpr int KT  = 32;
    constexpr int NT  = (BM / 8) * (BN / 8);
    constexpr int XS  = BM + 4;
    constexpr int WS  = BN + 4;
    constexpr int TRG = BM / 8;

    __shared__ float Xs[KT * XS];
    __shared__ float Ws[KT * WS];

    const int tid  = threadIdx.x;
    const int lane = tid & 63;
    const int hi   = tid >> 6;
    const int trl  = lane & 7;
    const int tcl  = (lane >> 3) & 7;
    const int tr   = trl + 8 * (hi % (TRG / 8));
    const int tc   = tcl + 8 * (hi / (TRG / 8));

    const int row0 = blockIdx.x * BM;

    float acc[8][8];
    #pragma unroll
    for (int i = 0; i < 8; ++i)
        #pragma unroll
        for (int j = 0; j < 8; ++j) acc[i][j] = 0.f;

    for (int kt = 0; kt < K; kt += KT) {
        __syncthreads();
        for (int idx = tid; idx < BM * (KT / 4); idx += NT) {
            int r  = idx / (KT / 4);
            int f4 = idx % (KT / 4);
            int gr = row0 + r;
            float4 v = make_float4(0.f, 0.f, 0.f, 0.f);
            if (gr < N) v = ((const float4*)(X + (size_t)gr * K + kt))[f4];
            Xs[(f4 * 4 + 0) * XS + r] = v.x;
            Xs[(f4 * 4 + 1) * XS + r] = v.y;
            Xs[(f4 * 4 + 2) * XS + r] = v.z;
            Xs[(f4 * 4 + 3) * XS + r] = v.w;
        }
        for (int idx = tid; idx < KT * (BN / 4); idx += NT) {
            int kk = idx / (BN / 4);
            int j  = idx % (BN / 4);
            float4 v = ((const float4*)(W + (size_t)(kt + kk) * BN))[j];
            *(float4*)&Ws[kk * WS + 4 * j] = v;
        }
        __syncthreads();

        #pragma unroll 4
        for (int k = 0; k < KT; ++k) {
            float4 x0 = *(const float4*)&Xs[k * XS + tr * 8];
            float4 x1 = *(const float4*)&Xs[k * XS + tr * 8 + 4];
            float4 w0 = *(const float4*)&Ws[k * WS + tc * 8];
            float4 w1 = *(const float4*)&Ws[k * WS + tc * 8 + 4];
            float xr[8] = {x0.x, x0.y, x0.z, x0.w, x1.x, x1.y, x1.z, x1.w};
            float wr[8] = {w0.x, w0.y, w0.z, w0.w, w1.x, w1.y, w1.z, w1.w};
            #pragma unroll
            for (int i = 0; i < 8; ++i)
                #pragma unroll
                for (int j = 0; j < 8; ++j)
                    acc[i][j] = fmaf(xr[i], wr[j], acc[i][j]);
        }
    }

    #pragma unroll
    for (int i = 0; i < 8; ++i) {
        int gr = row0 + tr * 8 + i;
        if (gr < N) {
            float dn = dinv[gr];
            half8 hv;
            #pragma unroll
            for (int q = 0; q < 4; ++q)
                hv.h[q] = __floats2half2_rn(dn * acc[i][2 * q], dn * acc[i][2 * q + 1]);
            *(half8*)(g + (size_t)gr * BN + tc * 8) = hv;
        }
    }
}

// ---------------- CSR aggregation + finalize ----------------
// One 64-lane wave per dst node, fp16 gathers, fp32 accumulate.

template<int FO, bool RELU>
__global__ __launch_bounds__(256) void aggregate_kernel(
    const __half* __restrict__ g, const int* __restrict__ rp, const int* __restrict__ deg,
    const int* __restrict__ csr, const float* __restrict__ dinv,
    const float* __restrict__ bias, float* __restrict__ out, int N)
{
    constexpr int PER = FO / 64;   // 2 (FO=128) or 1 (FO=64)
    int gid  = blockIdx.x * 256 + threadIdx.x;
    int node = gid >> 6;
    int lane = gid & 63;
    if (node >= N) return;

    int start = rp[node];
    int dg    = deg[node];

    float a0 = 0.f, a1 = 0.f;
    if (PER == 2) {
        float2 sv = __half22float2(*(const __half2*)(g + (size_t)node * FO + lane * 2));
        a0 = sv.x; a1 = sv.y;                      // self-loop term
    } else {
        a0 = __half2float(g[(size_t)node * FO + lane]);
    }

    int j = 0;
    for (; j + 3 < dg; j += 4) {
        int s0 = csr[start + j];
        int s1 = csr[start + j + 1];
        int s2 = csr[start + j + 2];
        int s3 = csr[start + j + 3];
        if (PER == 2) {
            float2 v0 = __half22float2(*(const __half2*)(g + (size_t)s0 * FO + lane * 2));
            float2 v1 = __half22float2(*(const __half2*)(g + (size_t)s1 * FO + lane * 2));
            float2 v2 = __half22float2(*(const __half2*)(g + (size_t)s2 * FO + lane * 2));
            float2 v3 = __half22float2(*(const __half2*)(g + (size_t)s3 * FO + lane * 2));
            a0 += (v0.x + v1.x) + (v2.x + v3.x);
            a1 += (v0.y + v1.y) + (v2.y + v3.y);
        } else {
            float v0 = __half2float(g[(size_t)s0 * FO + lane]);
            float v1 = __half2float(g[(size_t)s1 * FO + lane]);
            float v2 = __half2float(g[(size_t)s2 * FO + lane]);
            float v3 = __half2float(g[(size_t)s3 * FO + lane]);
            a0 += (v0 + v1) + (v2 + v3);
        }
    }
    for (; j < dg; ++j) {
        int s0 = csr[start + j];
        if (PER == 2) {
            float2 v0 = __half22float2(*(const __half2*)(g + (size_t)s0 * FO + lane * 2));
            a0 += v0.x; a1 += v0.y;
        } else {
            a0 += __half2float(g[(size_t)s0 * FO + lane]);
        }
    }

    float dn = dinv[node];
    if (PER == 2) {
        float2 bb = *(const float2*)(bias + lane * 2);
        float ox = fmaf(dn, a0, bb.x);
        float oy = fmaf(dn, a1, bb.y);
        if (RELU) { ox = fmaxf(ox, 0.f); oy = fmaxf(oy, 0.f); }
        *(float2*)(out + (size_t)node * FO + lane * 2) = make_float2(ox, oy);
    } else {
        float o = fmaf(dn, a0, bias[lane]);
        if (RELU) o = fmaxf(o, 0.f);
        out[(size_t)node * FO + lane] = o;
    }
}

// ---------------- launch ----------------

extern "C" void kernel_launch(void* const* d_in, const int* in_sizes, int n_in,
                              void* d_out, int out_size, void* d_ws, size_t ws_size,
                              hipStream_t stream) {
    const float* x  = (const float*)d_in[0];
    const int*   ei = (const int*)d_in[1];    // harness passes integer inputs as int32
    const float* W0 = (const float*)d_in[2];
    const float* b0 = (const float*)d_in[3];
    const float* W1 = (const float*)d_in[4];
    const float* b1 = (const float*)d_in[5];
    const float* W2 = (const float*)d_in[6];
    const float* b2 = (const float*)d_in[7];
    float* out = (float*)d_out;

    const int N = in_sizes[0] / F_IN;
    const int E = in_sizes[1] / 2;
    const int* src = ei;
    const int* dst = ei + E;

    char* ws = (char*)d_ws;
    size_t off = 0;
    __half* bufA  = (__half*)(ws + off); off += (size_t)N * 128 * 2;  // g (fp16)
    float* bufB   = (float*)(ws + off); off += (size_t)N * 128 * 4;   // features (fp32)
    float* dinv   = (float*)(ws + off); off += (size_t)N * 4;
    int*   deg    = (int*)  (ws + off); off += (size_t)N * 4;
    int*   rowptr = (int*)  (ws + off); off += (size_t)N * 4;
    int*   cursor = (int*)  (ws + off); off += (size_t)N * 4;
    int*   bsum   = (int*)  (ws + off); off += 256 * 4;
    int*   csr    = (int*)  (ws + off); off += (size_t)E * 4;

    const int nb_nodes = (N + 255) / 256;   // 196 blocks -> fits scan_bsum
    const int nb_edges = (E + 255) / 256;
    const int nb_aggr  = (N * 64 + 255) / 256;

    zero_int_kernel<<<nb_nodes, 256, 0, stream>>>(deg, N);
    deg_kernel<<<nb_edges, 256, 0, stream>>>(dst, deg, E);
    dinv_kernel<<<nb_nodes, 256, 0, stream>>>(deg, dinv, N);
    scan_blocks<<<nb_nodes, 256, 0, stream>>>(deg, rowptr, bsum, N);
    scan_bsum<<<1, 256, 0, stream>>>(bsum, nb_nodes);
    add_offsets_kernel<<<nb_nodes, 256, 0, stream>>>(rowptr, bsum, cursor, N);
    build_csr_kernel<<<nb_edges, 256, 0, stream>>>(src, dst, cursor, csr, E);

    // ---- layer 0: x -> bufA (g fp16) -> bufB ----
    gemm8x8_kernel<64, 128><<<(N + 63) / 64, 128, 0, stream>>>(x, W0, dinv, bufA, N);
    aggregate_kernel<128, true><<<nb_aggr, 256, 0, stream>>>(bufA, rowptr, deg, csr, dinv, b0, bufB, N);

    // ---- layer 1: bufB -> bufA (g fp16) -> bufB ----
    gemm8x8_kernel<64, 128><<<(N + 63) / 64, 128, 0, stream>>>(bufB, W1, dinv, bufA, N);
    aggregate_kernel<128, true><<<nb_aggr, 256, 0, stream>>>(bufA, rowptr, deg, csr, dinv, b1, bufB, N);

    // ---- layer 2: bufB -> bufA (g fp16, N*64) -> out ----
    gemm8x8_kernel<128, 64><<<(N + 127) / 128, 128, 0, stream>>>(bufB, W2, dinv, bufA, N);
    aggregate_kernel<64, false><<<nb_aggr, 256, 0, stream>>>(bufA, rowptr, deg, csr, dinv, b2, out, N);
}

// Round 7
// 290.124 us; speedup vs baseline: 13.1910x; 1.1244x over previous
//
#include <hip/hip_runtime.h>
#include <hip/hip_fp16.h>

#define F_IN 128

struct alignas(16) half8 { __half2 h[4]; };

// ---------------- degree / dinv ----------------

__global__ void zero_int_kernel(int* __restrict__ p, int n) {
    int i = blockIdx.x * blockDim.x + threadIdx.x;
    if (i < n) p[i] = 0;
}

__global__ void deg_kernel(const int* __restrict__ dst, int* __restrict__ deg, int E) {
    int i = blockIdx.x * blockDim.x + threadIdx.x;
    if (i < E) atomicAdd(&deg[dst[i]], 1);
}

__global__ void dinv_kernel(const int* __restrict__ deg, float* __restrict__ dinv, int N) {
    int i = blockIdx.x * blockDim.x + threadIdx.x;
    if (i < N) dinv[i] = rsqrtf((float)(deg[i] + 1));  // +1 self-loop; always > 0
}

// ---------------- CSR build: exclusive scan of deg + cursor placement ----------------

__global__ void scan_blocks(const int* __restrict__ deg, int* __restrict__ rp,
                            int* __restrict__ bsum, int N) {
    __shared__ int tmp[256];
    int t = threadIdx.x, i = blockIdx.x * 256 + t;
    int v = (i < N) ? deg[i] : 0;
    tmp[t] = v;
    __syncthreads();
    for (int off = 1; off < 256; off <<= 1) {
        int a = (t >= off) ? tmp[t - off] : 0;
        __syncthreads();
        tmp[t] += a;
        __syncthreads();
    }
    if (i < N) rp[i] = tmp[t] - v;
    if (t == 255) bsum[blockIdx.x] = tmp[255];
}

__global__ void scan_bsum(int* __restrict__ bsum, int nb) {   // nb <= 256
    __shared__ int tmp[256];
    int t = threadIdx.x;
    int v = (t < nb) ? bsum[t] : 0;
    tmp[t] = v;
    __syncthreads();
    for (int off = 1; off < 256; off <<= 1) {
        int a = (t >= off) ? tmp[t - off] : 0;
        __syncthreads();
        tmp[t] += a;
        __syncthreads();
    }
    if (t < nb) bsum[t] = tmp[t] - v;
}

__global__ void add_offsets_kernel(int* __restrict__ rp, const int* __restrict__ bsum,
                                   int* __restrict__ cursor, int N) {
    int i = blockIdx.x * 256 + threadIdx.x;
    if (i < N) {
        int r = rp[i] + bsum[blockIdx.x];
        rp[i] = r;
        cursor[i] = r;
    }
}

__global__ void build_csr_kernel(const int* __restrict__ src, const int* __restrict__ dst,
                                 int* __restrict__ cursor, int* __restrict__ csr_src, int E) {
    int e = blockIdx.x * 256 + threadIdx.x;
    if (e < E) {
        int pos = atomicAdd(&cursor[dst[e]], 1);
        csr_src[pos] = src[e];
    }
}

// ---------------- GEMM: g = fp16(dinv * (X @ W)), TMx8 register tile ----------------
// 256 threads, 4 waves/block for occupancy (R6 was grid-starved at 2 waves).
// Xs staged transposed [k][row]; tr = tid % (BM/TM) keeps wave X-reads at
// <=2-way bank aliasing (free), W reads broadcast across row-groups.

template<int BM, int BN, int TM>
__global__ __launch_bounds__((BM / TM) * (BN / 8)) void gemm_rt_kernel(
    const float* __restrict__ X, const float* __restrict__ W,
    const float* __restrict__ dinv, __half* __restrict__ g, int N)
{
    constexpr int K  = 128;
    constexpr int KT = 32;
    constexpr int TN = 8;
    constexpr int RT = BM / TM;
    constexpr int CT = BN / TN;
    constexpr int NT = RT * CT;
    constexpr int XS = BM + 4;
    constexpr int WS = BN + 4;

    __shared__ float Xs[KT * XS];
    __shared__ float Ws[KT * WS];

    const int tid = threadIdx.x;
    const int tr  = tid % RT;
    const int tc  = tid / RT;

    const int row0 = blockIdx.x * BM;

    float acc[TM][TN];
    #pragma unroll
    for (int i = 0; i < TM; ++i)
        #pragma unroll
        for (int j = 0; j < TN; ++j) acc[i][j] = 0.f;

    for (int kt = 0; kt < K; kt += KT) {
        __syncthreads();
        // stage X transposed: global [row][kt+4f4+ii] -> Xs[(4f4+ii)][row]
        for (int idx = tid; idx < BM * (KT / 4); idx += NT) {
            int r  = idx / (KT / 4);
            int f4 = idx % (KT / 4);
            int gr = row0 + r;
            float4 v = make_float4(0.f, 0.f, 0.f, 0.f);
            if (gr < N) v = ((const float4*)(X + (size_t)gr * K + kt))[f4];
            Xs[(f4 * 4 + 0) * XS + r] = v.x;
            Xs[(f4 * 4 + 1) * XS + r] = v.y;
            Xs[(f4 * 4 + 2) * XS + r] = v.z;
            Xs[(f4 * 4 + 3) * XS + r] = v.w;
        }
        // stage W: [kt+kk][4j]
        for (int idx = tid; idx < KT * (BN / 4); idx += NT) {
            int kk = idx / (BN / 4);
            int j  = idx % (BN / 4);
            float4 v = ((const float4*)(W + (size_t)(kt + kk) * BN))[j];
            *(float4*)&Ws[kk * WS + 4 * j] = v;
        }
        __syncthreads();

        #pragma unroll 4
        for (int k = 0; k < KT; ++k) {
            float xr[TM];
            if (TM == 4) {
                float4 x0 = *(const float4*)&Xs[k * XS + tr * TM];
                xr[0] = x0.x; xr[1] = x0.y; xr[2] = x0.z; xr[3] = x0.w;
            } else {  // TM == 2
                float2 x0 = *(const float2*)&Xs[k * XS + tr * TM];
                xr[0] = x0.x; xr[1] = x0.y;
            }
            float4 w0 = *(const float4*)&Ws[k * WS + tc * 8];
            float4 w1 = *(const float4*)&Ws[k * WS + tc * 8 + 4];
            float wr[8] = {w0.x, w0.y, w0.z, w0.w, w1.x, w1.y, w1.z, w1.w};
            #pragma unroll
            for (int i = 0; i < TM; ++i)
                #pragma unroll
                for (int j = 0; j < TN; ++j)
                    acc[i][j] = fmaf(xr[i], wr[j], acc[i][j]);
        }
    }

    #pragma unroll
    for (int i = 0; i < TM; ++i) {
        int gr = row0 + tr * TM + i;
        if (gr < N) {
            float dn = dinv[gr];
            half8 hv;
            #pragma unroll
            for (int q = 0; q < 4; ++q)
                hv.h[q] = __floats2half2_rn(dn * acc[i][2 * q], dn * acc[i][2 * q + 1]);
            *(half8*)(g + (size_t)gr * BN + tc * 8) = hv;
        }
    }
}

// ---------------- CSR aggregation + finalize ----------------
// One 64-lane wave per dst node, fp16 gathers, fp32 accumulate.

template<int FO, bool RELU>
__global__ __launch_bounds__(256) void aggregate_kernel(
    const __half* __restrict__ g, const int* __restrict__ rp, const int* __restrict__ deg,
    const int* __restrict__ csr, const float* __restrict__ dinv,
    const float* __restrict__ bias, float* __restrict__ out, int N)
{
    constexpr int PER = FO / 64;   // 2 (FO=128) or 1 (FO=64)
    int gid  = blockIdx.x * 256 + threadIdx.x;
    int node = gid >> 6;
    int lane = gid & 63;
    if (node >= N) return;

    int start = rp[node];
    int dg    = deg[node];

    float a0 = 0.f, a1 = 0.f;
    if (PER == 2) {
        float2 sv = __half22float2(*(const __half2*)(g + (size_t)node * FO + lane * 2));
        a0 = sv.x; a1 = sv.y;                      // self-loop term
    } else {
        a0 = __half2float(g[(size_t)node * FO + lane]);
    }

    int j = 0;
    for (; j + 3 < dg; j += 4) {
        int s0 = csr[start + j];
        int s1 = csr[start + j + 1];
        int s2 = csr[start + j + 2];
        int s3 = csr[start + j + 3];
        if (PER == 2) {
            float2 v0 = __half22float2(*(const __half2*)(g + (size_t)s0 * FO + lane * 2));
            float2 v1 = __half22float2(*(const __half2*)(g + (size_t)s1 * FO + lane * 2));
            float2 v2 = __half22float2(*(const __half2*)(g + (size_t)s2 * FO + lane * 2));
            float2 v3 = __half22float2(*(const __half2*)(g + (size_t)s3 * FO + lane * 2));
            a0 += (v0.x + v1.x) + (v2.x + v3.x);
            a1 += (v0.y + v1.y) + (v2.y + v3.y);
        } else {
            float v0 = __half2float(g[(size_t)s0 * FO + lane]);
            float v1 = __half2float(g[(size_t)s1 * FO + lane]);
            float v2 = __half2float(g[(size_t)s2 * FO + lane]);
            float v3 = __half2float(g[(size_t)s3 * FO + lane]);
            a0 += (v0 + v1) + (v2 + v3);
        }
    }
    for (; j < dg; ++j) {
        int s0 = csr[start + j];
        if (PER == 2) {
            float2 v0 = __half22float2(*(const __half2*)(g + (size_t)s0 * FO + lane * 2));
            a0 += v0.x; a1 += v0.y;
        } else {
            a0 += __half2float(g[(size_t)s0 * FO + lane]);
        }
    }

    float dn = dinv[node];
    if (PER == 2) {
        float2 bb = *(const float2*)(bias + lane * 2);
        float ox = fmaf(dn, a0, bb.x);
        float oy = fmaf(dn, a1, bb.y);
        if (RELU) { ox = fmaxf(ox, 0.f); oy = fmaxf(oy, 0.f); }
        *(float2*)(out + (size_t)node * FO + lane * 2) = make_float2(ox, oy);
    } else {
        float o = fmaf(dn, a0, bias[lane]);
        if (RELU) o = fmaxf(o, 0.f);
        out[(size_t)node * FO + lane] = o;
    }
}

// ---------------- launch ----------------

extern "C" void kernel_launch(void* const* d_in, const int* in_sizes, int n_in,
                              void* d_out, int out_size, void* d_ws, size_t ws_size,
                              hipStream_t stream) {
    const float* x  = (const float*)d_in[0];
    const int*   ei = (const int*)d_in[1];    // harness passes integer inputs as int32
    const float* W0 = (const float*)d_in[2];
    const float* b0 = (const float*)d_in[3];
    const float* W1 = (const float*)d_in[4];
    const float* b1 = (const float*)d_in[5];
    const float* W2 = (const float*)d_in[6];
    const float* b2 = (const float*)d_in[7];
    float* out = (float*)d_out;

    const int N = in_sizes[0] / F_IN;
    const int E = in_sizes[1] / 2;
    const int* src = ei;
    const int* dst = ei + E;

    char* ws = (char*)d_ws;
    size_t off = 0;
    __half* bufA  = (__half*)(ws + off); off += (size_t)N * 128 * 2;  // g (fp16)
    float* bufB   = (float*)(ws + off); off += (size_t)N * 128 * 4;   // features (fp32)
    float* dinv   = (float*)(ws + off); off += (size_t)N * 4;
    int*   deg    = (int*)  (ws + off); off += (size_t)N * 4;
    int*   rowptr = (int*)  (ws + off); off += (size_t)N * 4;
    int*   cursor = (int*)  (ws + off); off += (size_t)N * 4;
    int*   bsum   = (int*)  (ws + off); off += 256 * 4;
    int*   csr    = (int*)  (ws + off); off += (size_t)E * 4;

    const int nb_nodes = (N + 255) / 256;   // 196 blocks -> fits scan_bsum
    const int nb_edges = (E + 255) / 256;
    const int nb_aggr  = (N * 64 + 255) / 256;

    zero_int_kernel<<<nb_nodes, 256, 0, stream>>>(deg, N);
    deg_kernel<<<nb_edges, 256, 0, stream>>>(dst, deg, E);
    dinv_kernel<<<nb_nodes, 256, 0, stream>>>(deg, dinv, N);
    scan_blocks<<<nb_nodes, 256, 0, stream>>>(deg, rowptr, bsum, N);
    scan_bsum<<<1, 256, 0, stream>>>(bsum, nb_nodes);
    add_offsets_kernel<<<nb_nodes, 256, 0, stream>>>(rowptr, bsum, cursor, N);
    build_csr_kernel<<<nb_edges, 256, 0, stream>>>(src, dst, cursor, csr, E);

    // ---- layer 0: x -> bufA (g fp16) -> bufB ----
    gemm_rt_kernel<64, 128, 4><<<(N + 63) / 64, 256, 0, stream>>>(x, W0, dinv, bufA, N);
    aggregate_kernel<128, true><<<nb_aggr, 256, 0, stream>>>(bufA, rowptr, deg, csr, dinv, b0, bufB, N);

    // ---- layer 1: bufB -> bufA (g fp16) -> bufB ----
    gemm_rt_kernel<64, 128, 4><<<(N + 63) / 64, 256, 0, stream>>>(bufB, W1, dinv, bufA, N);
    aggregate_kernel<128, true><<<nb_aggr, 256, 0, stream>>>(bufA, rowptr, deg, csr, dinv, b1, bufB, N);

    // ---- layer 2: bufB -> bufA (g fp16, N*64) -> out ----
    gemm_rt_kernel<64, 64, 2><<<(N + 63) / 64, 256, 0, stream>>>(bufB, W2, dinv, bufA, N);
    aggregate_kernel<64, false><<<nb_aggr, 256, 0, stream>>>(bufA, rowptr, deg, csr, dinv, b2, out, N);
}

// Round 8
// 283.040 us; speedup vs baseline: 13.5212x; 1.0250x over previous
//
#include <hip/hip_runtime.h>
#include <hip/hip_fp16.h>

#define F_IN 128
#define NPART 8

struct alignas(16) half8 { __half2 h[4]; };

// ---------------- degree / dinv ----------------

__global__ void zero_int_kernel(int* __restrict__ p, int n) {
    int i = blockIdx.x * blockDim.x + threadIdx.x;
    if (i < n) p[i] = 0;
}

__global__ void deg_kernel(const int* __restrict__ dst, int* __restrict__ deg, int E) {
    int i = blockIdx.x * blockDim.x + threadIdx.x;
    if (i < E) atomicAdd(&deg[dst[i]], 1);
}

__global__ void dinv_kernel(const int* __restrict__ deg, float* __restrict__ dinv, int N) {
    int i = blockIdx.x * blockDim.x + threadIdx.x;
    if (i < N) dinv[i] = rsqrtf((float)(deg[i] + 1));  // +1 self-loop; always > 0
}

// ---------------- CSR build: exclusive scan of deg + partitioned placement ----------------

__global__ void scan_blocks(const int* __restrict__ deg, int* __restrict__ rp,
                            int* __restrict__ bsum, int N) {
    __shared__ int tmp[256];
    int t = threadIdx.x, i = blockIdx.x * 256 + t;
    int v = (i < N) ? deg[i] : 0;
    tmp[t] = v;
    __syncthreads();
    for (int off = 1; off < 256; off <<= 1) {
        int a = (t >= off) ? tmp[t - off] : 0;
        __syncthreads();
        tmp[t] += a;
        __syncthreads();
    }
    if (i < N) rp[i] = tmp[t] - v;
    if (t == 255) bsum[blockIdx.x] = tmp[255];
}

__global__ void scan_bsum(int* __restrict__ bsum, int nb) {   // nb <= 256
    __shared__ int tmp[256];
    int t = threadIdx.x;
    int v = (t < nb) ? bsum[t] : 0;
    tmp[t] = v;
    __syncthreads();
    for (int off = 1; off < 256; off <<= 1) {
        int a = (t >= off) ? tmp[t - off] : 0;
        __syncthreads();
        tmp[t] += a;
        __syncthreads();
    }
    if (t < nb) bsum[t] = tmp[t] - v;
}

__global__ void add_offsets_kernel(int* __restrict__ rp, const int* __restrict__ bsum,
                                   int* __restrict__ cursor, int N) {
    int i = blockIdx.x * 256 + threadIdx.x;
    if (i < N) {
        int r = rp[i] + bsum[blockIdx.x];
        rp[i] = r;
        cursor[i] = r;
    }
}

// dst-partitioned, XCD-affine CSR build. Partition p owns dst in [p*ps,(p+1)*ps);
// blockIdx%NPART -> partition, so (round-robin dispatch) each partition's cursor
// and csr slice stay in one XCD's L2 -> scattered u16 stores coalesce before
// writeback instead of 1 line-evict per edge.
__global__ __launch_bounds__(256) void build_csr_kernel(
    const int* __restrict__ src, const int* __restrict__ dst,
    int* __restrict__ cursor, unsigned short* __restrict__ csr_src,
    int E, int psize)
{
    const int part = blockIdx.x % NPART;
    const int bslot = blockIdx.x / NPART;
    const int nb = gridDim.x / NPART;
    const int lo = part * psize;
    const int hi = lo + psize;           // last partition: hi >= N, harmless
    for (int e = bslot * 256 + threadIdx.x; e < E; e += nb * 256) {
        int d = dst[e];
        if (d >= lo && d < hi) {
            int pos = atomicAdd(&cursor[d], 1);
            csr_src[pos] = (unsigned short)src[e];
        }
    }
}

// ---------------- GEMM: g = fp16(dinv * (X @ W)), TMx8 register tile ----------------
// 256 threads, 4 waves/block. Xs staged transposed [k][row] (converted to f32
// if X is fp16); tr = tid % (BM/TM) keeps wave X-reads at <=2-way bank aliasing.

template<int BM, int BN, int TM, typename XT>
__global__ __launch_bounds__((BM / TM) * (BN / 8)) void gemm_rt_kernel(
    const XT* __restrict__ X, const float* __restrict__ W,
    const float* __restrict__ dinv, __half* __restrict__ g, int N)
{
    constexpr int K  = 128;
    constexpr int KT = 32;
    constexpr int TN = 8;
    constexpr int RT = BM / TM;
    constexpr int CT = BN / TN;
    constexpr int NT = RT * CT;
    constexpr int XS = BM + 4;
    constexpr int WS = BN + 4;

    __shared__ float Xs[KT * XS];
    __shared__ float Ws[KT * WS];

    const int tid = threadIdx.x;
    const int tr  = tid % RT;
    const int tc  = tid / RT;

    const int row0 = blockIdx.x * BM;

    float acc[TM][TN];
    #pragma unroll
    for (int i = 0; i < TM; ++i)
        #pragma unroll
        for (int j = 0; j < TN; ++j) acc[i][j] = 0.f;

    for (int kt = 0; kt < K; kt += KT) {
        __syncthreads();
        if constexpr (sizeof(XT) == 4) {
            // fp32 X: float4 per (row, 4-k)
            for (int idx = tid; idx < BM * (KT / 4); idx += NT) {
                int r  = idx / (KT / 4);
                int f4 = idx % (KT / 4);
                int gr = row0 + r;
                float4 v = make_float4(0.f, 0.f, 0.f, 0.f);
                if (gr < N) v = ((const float4*)((const float*)X + (size_t)gr * K + kt))[f4];
                Xs[(f4 * 4 + 0) * XS + r] = v.x;
                Xs[(f4 * 4 + 1) * XS + r] = v.y;
                Xs[(f4 * 4 + 2) * XS + r] = v.z;
                Xs[(f4 * 4 + 3) * XS + r] = v.w;
            }
        } else {
            // fp16 X: half8 per (row, 8-k)
            for (int idx = tid; idx < BM * (KT / 8); idx += NT) {
                int r  = idx / (KT / 8);
                int f8 = idx % (KT / 8);
                int gr = row0 + r;
                half8 v;
                #pragma unroll
                for (int q = 0; q < 4; ++q) v.h[q] = __floats2half2_rn(0.f, 0.f);
                if (gr < N) v = ((const half8*)((const __half*)X + (size_t)gr * K + kt))[f8];
                #pragma unroll
                for (int q = 0; q < 4; ++q) {
                    float2 f = __half22float2(v.h[q]);
                    Xs[(f8 * 8 + 2 * q + 0) * XS + r] = f.x;
                    Xs[(f8 * 8 + 2 * q + 1) * XS + r] = f.y;
                }
            }
        }
        for (int idx = tid; idx < KT * (BN / 4); idx += NT) {
            int kk = idx / (BN / 4);
            int j  = idx % (BN / 4);
            float4 v = ((const float4*)(W + (size_t)(kt + kk) * BN))[j];
            *(float4*)&Ws[kk * WS + 4 * j] = v;
        }
        __syncthreads();

        #pragma unroll 4
        for (int k = 0; k < KT; ++k) {
            float xr[TM];
            if (TM == 4) {
                float4 x0 = *(const float4*)&Xs[k * XS + tr * TM];
                xr[0] = x0.x; xr[1] = x0.y; xr[2] = x0.z; xr[3] = x0.w;
            } else {  // TM == 2
                float2 x0 = *(const float2*)&Xs[k * XS + tr * TM];
                xr[0] = x0.x; xr[1] = x0.y;
            }
            float4 w0 = *(const float4*)&Ws[k * WS + tc * 8];
            float4 w1 = *(const float4*)&Ws[k * WS + tc * 8 + 4];
            float wr[8] = {w0.x, w0.y, w0.z, w0.w, w1.x, w1.y, w1.z, w1.w};
            #pragma unroll
            for (int i = 0; i < TM; ++i)
                #pragma unroll
                for (int j = 0; j < TN; ++j)
                    acc[i][j] = fmaf(xr[i], wr[j], acc[i][j]);
        }
    }

    #pragma unroll
    for (int i = 0; i < TM; ++i) {
        int gr = row0 + tr * TM + i;
        if (gr < N) {
            float dn = dinv[gr];
            half8 hv;
            #pragma unroll
            for (int q = 0; q < 4; ++q)
                hv.h[q] = __floats2half2_rn(dn * acc[i][2 * q], dn * acc[i][2 * q + 1]);
            *(half8*)(g + (size_t)gr * BN + tc * 8) = hv;
        }
    }
}

// ---------------- CSR aggregation + finalize ----------------
// One 64-lane wave per dst node, fp16 gathers, fp32 accumulate, OT output.

template<int FO, bool RELU, typename OT>
__global__ __launch_bounds__(256) void aggregate_kernel(
    const __half* __restrict__ g, const int* __restrict__ rp, const int* __restrict__ deg,
    const unsigned short* __restrict__ csr, const float* __restrict__ dinv,
    const float* __restrict__ bias, OT* __restrict__ out, int N)
{
    constexpr int PER = FO / 64;   // 2 (FO=128) or 1 (FO=64)
    int gid  = blockIdx.x * 256 + threadIdx.x;
    int node = gid >> 6;
    int lane = gid & 63;
    if (node >= N) return;

    int start = rp[node];
    int dg    = deg[node];

    float a0 = 0.f, a1 = 0.f;
    if (PER == 2) {
        float2 sv = __half22float2(*(const __half2*)(g + (size_t)node * FO + lane * 2));
        a0 = sv.x; a1 = sv.y;                      // self-loop term
    } else {
        a0 = __half2float(g[(size_t)node * FO + lane]);
    }

    int j = 0;
    for (; j + 3 < dg; j += 4) {
        int s0 = csr[start + j];
        int s1 = csr[start + j + 1];
        int s2 = csr[start + j + 2];
        int s3 = csr[start + j + 3];
        if (PER == 2) {
            float2 v0 = __half22float2(*(const __half2*)(g + (size_t)s0 * FO + lane * 2));
            float2 v1 = __half22float2(*(const __half2*)(g + (size_t)s1 * FO + lane * 2));
            float2 v2 = __half22float2(*(const __half2*)(g + (size_t)s2 * FO + lane * 2));
            float2 v3 = __half22float2(*(const __half2*)(g + (size_t)s3 * FO + lane * 2));
            a0 += (v0.x + v1.x) + (v2.x + v3.x);
            a1 += (v0.y + v1.y) + (v2.y + v3.y);
        } else {
            float v0 = __half2float(g[(size_t)s0 * FO + lane]);
            float v1 = __half2float(g[(size_t)s1 * FO + lane]);
            float v2 = __half2float(g[(size_t)s2 * FO + lane]);
            float v3 = __half2float(g[(size_t)s3 * FO + lane]);
            a0 += (v0 + v1) + (v2 + v3);
        }
    }
    for (; j < dg; ++j) {
        int s0 = csr[start + j];
        if (PER == 2) {
            float2 v0 = __half22float2(*(const __half2*)(g + (size_t)s0 * FO + lane * 2));
            a0 += v0.x; a1 += v0.y;
        } else {
            a0 += __half2float(g[(size_t)s0 * FO + lane]);
        }
    }

    float dn = dinv[node];
    if (PER == 2) {
        float2 bb = *(const float2*)(bias + lane * 2);
        float ox = fmaf(dn, a0, bb.x);
        float oy = fmaf(dn, a1, bb.y);
        if (RELU) { ox = fmaxf(ox, 0.f); oy = fmaxf(oy, 0.f); }
        if constexpr (sizeof(OT) == 2) {
            *(__half2*)((__half*)out + (size_t)node * FO + lane * 2) = __floats2half2_rn(ox, oy);
        } else {
            *(float2*)((float*)out + (size_t)node * FO + lane * 2) = make_float2(ox, oy);
        }
    } else {
        float o = fmaf(dn, a0, bias[lane]);
        if (RELU) o = fmaxf(o, 0.f);
        if constexpr (sizeof(OT) == 2) {
            ((__half*)out)[(size_t)node * FO + lane] = __float2half_rn(o);
        } else {
            ((float*)out)[(size_t)node * FO + lane] = o;
        }
    }
}

// ---------------- launch ----------------

extern "C" void kernel_launch(void* const* d_in, const int* in_sizes, int n_in,
                              void* d_out, int out_size, void* d_ws, size_t ws_size,
                              hipStream_t stream) {
    const float* x  = (const float*)d_in[0];
    const int*   ei = (const int*)d_in[1];    // harness passes integer inputs as int32
    const float* W0 = (const float*)d_in[2];
    const float* b0 = (const float*)d_in[3];
    const float* W1 = (const float*)d_in[4];
    const float* b1 = (const float*)d_in[5];
    const float* W2 = (const float*)d_in[6];
    const float* b2 = (const float*)d_in[7];
    float* out = (float*)d_out;

    const int N = in_sizes[0] / F_IN;
    const int E = in_sizes[1] / 2;
    const int* src = ei;
    const int* dst = ei + E;

    char* ws = (char*)d_ws;
    size_t off = 0;
    __half* bufA  = (__half*)(ws + off); off += (size_t)N * 128 * 2;  // g (fp16)
    __half* bufB  = (__half*)(ws + off); off += (size_t)N * 128 * 2;  // features (fp16)
    float* dinv   = (float*)(ws + off); off += (size_t)N * 4;
    int*   deg    = (int*)  (ws + off); off += (size_t)N * 4;
    int*   rowptr = (int*)  (ws + off); off += (size_t)N * 4;
    int*   cursor = (int*)  (ws + off); off += (size_t)N * 4;
    int*   bsum   = (int*)  (ws + off); off += 256 * 4;
    unsigned short* csr = (unsigned short*)(ws + off); off += (size_t)E * 2;

    const int nb_nodes = (N + 255) / 256;   // 196 blocks -> fits scan_bsum
    const int nb_edges = (E + 255) / 256;
    const int nb_aggr  = (N * 64 + 255) / 256;
    const int psize    = (N + NPART - 1) / NPART;

    zero_int_kernel<<<nb_nodes, 256, 0, stream>>>(deg, N);
    deg_kernel<<<nb_edges, 256, 0, stream>>>(dst, deg, E);
    dinv_kernel<<<nb_nodes, 256, 0, stream>>>(deg, dinv, N);
    scan_blocks<<<nb_nodes, 256, 0, stream>>>(deg, rowptr, bsum, N);
    scan_bsum<<<1, 256, 0, stream>>>(bsum, nb_nodes);
    add_offsets_kernel<<<nb_nodes, 256, 0, stream>>>(rowptr, bsum, cursor, N);
    build_csr_kernel<<<NPART * 128, 256, 0, stream>>>(src, dst, cursor, csr, E, psize);

    // ---- layer 0: x (fp32) -> bufA (g fp16) -> bufB (fp16) ----
    gemm_rt_kernel<64, 128, 4, float><<<(N + 63) / 64, 256, 0, stream>>>(x, W0, dinv, bufA, N);
    aggregate_kernel<128, true, __half><<<nb_aggr, 256, 0, stream>>>(bufA, rowptr, deg, csr, dinv, b0, bufB, N);

    // ---- layer 1: bufB (fp16) -> bufA (g fp16) -> bufB (fp16) ----
    gemm_rt_kernel<64, 128, 4, __half><<<(N + 63) / 64, 256, 0, stream>>>(bufB, W1, dinv, bufA, N);
    aggregate_kernel<128, true, __half><<<nb_aggr, 256, 0, stream>>>(bufA, rowptr, deg, csr, dinv, b1, bufB, N);

    // ---- layer 2: bufB (fp16) -> bufA (g fp16, N*64) -> out (fp32) ----
    gemm_rt_kernel<64, 64, 2, __half><<<(N + 63) / 64, 256, 0, stream>>>(bufB, W2, dinv, bufA, N);
    aggregate_kernel<64, false, float><<<nb_aggr, 256, 0, stream>>>(bufA, rowptr, deg, csr, dinv, b2, out, N);
}

// Round 9
// 234.181 us; speedup vs baseline: 16.3422x; 1.2086x over previous
//
#include <hip/hip_runtime.h>
#include <hip/hip_fp16.h>

#define F_IN 128
#define NPART 8

struct alignas(16) half8 { __half2 h[4]; };
typedef _Float16 f16x8 __attribute__((ext_vector_type(8)));
typedef float f32x4 __attribute__((ext_vector_type(4)));

// ---------------- prep: transpose+convert weights to fp16 Wt[n][k] ----------------

__global__ void prep_weights_kernel(const float* __restrict__ W0, const float* __restrict__ W1,
                                    const float* __restrict__ W2, __half* __restrict__ Wt0,
                                    __half* __restrict__ Wt1, __half* __restrict__ Wt2) {
    int idx = blockIdx.x * 256 + threadIdx.x;   // 0..40959
    if (idx < 16384) {                          // W0: [128][128]
        int k = idx >> 7, n = idx & 127;
        Wt0[n * 128 + k] = __float2half_rn(W0[idx]);
    } else if (idx < 32768) {                   // W1: [128][128]
        int j = idx - 16384;
        int k = j >> 7, n = j & 127;
        Wt1[n * 128 + k] = __float2half_rn(W1[j]);
    } else if (idx < 40960) {                   // W2: [128][64]
        int j = idx - 32768;
        int k = j >> 6, n = j & 63;
        Wt2[n * 128 + k] = __float2half_rn(W2[j]);
    }
}

// ---------------- degree ----------------

__global__ void zero_int_kernel(int* __restrict__ p, int n) {
    int i = blockIdx.x * blockDim.x + threadIdx.x;
    if (i < n) p[i] = 0;
}

__global__ void deg_kernel(const int* __restrict__ dst, int* __restrict__ deg, int E) {
    int i = blockIdx.x * blockDim.x + threadIdx.x;
    if (i < E) atomicAdd(&deg[dst[i]], 1);
}

// ---------------- CSR build: exclusive scan of deg + partitioned placement ----------------

__global__ void scan_blocks(const int* __restrict__ deg, int* __restrict__ rp,
                            int* __restrict__ bsum, int N) {
    __shared__ int tmp[256];
    int t = threadIdx.x, i = blockIdx.x * 256 + t;
    int v = (i < N) ? deg[i] : 0;
    tmp[t] = v;
    __syncthreads();
    for (int off = 1; off < 256; off <<= 1) {
        int a = (t >= off) ? tmp[t - off] : 0;
        __syncthreads();
        tmp[t] += a;
        __syncthreads();
    }
    if (i < N) rp[i] = tmp[t] - v;
    if (t == 255) bsum[blockIdx.x] = tmp[255];
}

__global__ void scan_bsum(int* __restrict__ bsum, int nb) {   // nb <= 256
    __shared__ int tmp[256];
    int t = threadIdx.x;
    int v = (t < nb) ? bsum[t] : 0;
    tmp[t] = v;
    __syncthreads();
    for (int off = 1; off < 256; off <<= 1) {
        int a = (t >= off) ? tmp[t - off] : 0;
        __syncthreads();
        tmp[t] += a;
        __syncthreads();
    }
    if (t < nb) bsum[t] = tmp[t] - v;
}

// also computes dinv (fused; deg is final here)
__global__ void add_offsets_kernel(int* __restrict__ rp, const int* __restrict__ bsum,
                                   int* __restrict__ cursor, const int* __restrict__ deg,
                                   float* __restrict__ dinv, int N) {
    int i = blockIdx.x * 256 + threadIdx.x;
    if (i < N) {
        int r = rp[i] + bsum[blockIdx.x];
        rp[i] = r;
        cursor[i] = r;
        dinv[i] = rsqrtf((float)(deg[i] + 1));   // +1 self-loop; always > 0
    }
}

// dst-partitioned, XCD-affine CSR build (u16 payload).
__global__ __launch_bounds__(256) void build_csr_kernel(
    const int* __restrict__ src, const int* __restrict__ dst,
    int* __restrict__ cursor, unsigned short* __restrict__ csr_src,
    int E, int psize)
{
    const int part = blockIdx.x % NPART;
    const int bslot = blockIdx.x / NPART;
    const int nb = gridDim.x / NPART;
    const int lo = part * psize;
    const int hi = lo + psize;
    for (int e = bslot * 256 + threadIdx.x; e < E; e += nb * 256) {
        int d = dst[e];
        if (d >= lo && d < hi) {
            int pos = atomicAdd(&cursor[d], 1);
            csr_src[pos] = (unsigned short)src[e];
        }
    }
}

// ---------------- MFMA GEMM: g = fp16(dinv * (X @ W)) ----------------
// BM=64 (4 waves x 16 rows), BN=128 or 64. A from global (row-major X),
// B = Wt[n][k] fp16 staged in LDS with +8-half row pad (16B-aligned, 2-way banks).
// Fragment maps: A: m=lane&15, k=ks*32+(lane>>4)*8+j ; B: n=lane&15, same k
// (identical k-map on both operands -> k-permutation cancels).
// C/D: col=lane&15, row=(lane>>4)*4+reg  [HW-verified m89/m91].

template<int BN, typename XT>
__global__ __launch_bounds__(256) void gemm_mfma_kernel(
    const XT* __restrict__ X, const __half* __restrict__ Wt,
    const float* __restrict__ dinv, __half* __restrict__ g, int N)
{
    constexpr int K  = 128;
    constexpr int KP = K + 8;
    constexpr int NT = BN / 16;
    __shared__ __half Ws[BN * KP];

    const int tid = threadIdx.x;
    for (int c = tid; c < BN * (K / 8); c += 256) {
        int n  = c >> 4;          // 16 chunks of 8 halves per row
        int k8 = c & 15;
        *(f16x8*)&Ws[n * KP + k8 * 8] =
            *(const f16x8*)((const _Float16*)Wt + n * K + k8 * 8);
    }
    __syncthreads();

    const int lane = tid & 63;
    const int w    = tid >> 6;
    const int lrow = lane & 15;
    const int kg   = lane >> 4;
    const int row0 = blockIdx.x * 64 + w * 16;
    const int gr   = row0 + lrow;

    f32x4 acc[NT];
    #pragma unroll
    for (int t = 0; t < NT; ++t) acc[t] = (f32x4){0.f, 0.f, 0.f, 0.f};

    #pragma unroll
    for (int ks = 0; ks < 4; ++ks) {
        const int k0 = ks * 32 + kg * 8;
        f16x8 a = {};
        if constexpr (sizeof(XT) == 4) {
            if (gr < N) {
                const float* p = (const float*)X + (size_t)gr * K + k0;
                float4 x0 = *(const float4*)p;
                float4 x1 = *(const float4*)(p + 4);
                a[0] = (_Float16)x0.x; a[1] = (_Float16)x0.y;
                a[2] = (_Float16)x0.z; a[3] = (_Float16)x0.w;
                a[4] = (_Float16)x1.x; a[5] = (_Float16)x1.y;
                a[6] = (_Float16)x1.z; a[7] = (_Float16)x1.w;
            }
        } else {
            if (gr < N)
                a = *(const f16x8*)((const _Float16*)X + (size_t)gr * K + k0);
        }
        #pragma unroll
        for (int t = 0; t < NT; ++t) {
            f16x8 b = *(const f16x8*)&Ws[(t * 16 + lrow) * KP + k0];
            acc[t] = __builtin_amdgcn_mfma_f32_16x16x32_f16(a, b, acc[t], 0, 0, 0);
        }
    }

    #pragma unroll
    for (int r = 0; r < 4; ++r) {
        int m = row0 + kg * 4 + r;
        if (m < N) {
            float dn = dinv[m];
            #pragma unroll
            for (int t = 0; t < NT; ++t)
                g[(size_t)m * BN + t * 16 + lrow] = __float2half_rn(dn * acc[t][r]);
        }
    }
}

// ---------------- CSR aggregation + finalize ----------------
// One 64-lane wave per dst node, fp16 gathers, fp32 accumulate, OT output.

template<int FO, bool RELU, typename OT>
__global__ __launch_bounds__(256) void aggregate_kernel(
    const __half* __restrict__ g, const int* __restrict__ rp, const int* __restrict__ deg,
    const unsigned short* __restrict__ csr, const float* __restrict__ dinv,
    const float* __restrict__ bias, OT* __restrict__ out, int N)
{
    constexpr int PER = FO / 64;   // 2 (FO=128) or 1 (FO=64)
    int gid  = blockIdx.x * 256 + threadIdx.x;
    int node = gid >> 6;
    int lane = gid & 63;
    if (node >= N) return;

    int start = rp[node];
    int dg    = deg[node];

    float a0 = 0.f, a1 = 0.f;
    if (PER == 2) {
        float2 sv = __half22float2(*(const __half2*)(g + (size_t)node * FO + lane * 2));
        a0 = sv.x; a1 = sv.y;                      // self-loop term
    } else {
        a0 = __half2float(g[(size_t)node * FO + lane]);
    }

    int j = 0;
    for (; j + 3 < dg; j += 4) {
        int s0 = csr[start + j];
        int s1 = csr[start + j + 1];
        int s2 = csr[start + j + 2];
        int s3 = csr[start + j + 3];
        if (PER == 2) {
            float2 v0 = __half22float2(*(const __half2*)(g + (size_t)s0 * FO + lane * 2));
            float2 v1 = __half22float2(*(const __half2*)(g + (size_t)s1 * FO + lane * 2));
            float2 v2 = __half22float2(*(const __half2*)(g + (size_t)s2 * FO + lane * 2));
            float2 v3 = __half22float2(*(const __half2*)(g + (size_t)s3 * FO + lane * 2));
            a0 += (v0.x + v1.x) + (v2.x + v3.x);
            a1 += (v0.y + v1.y) + (v2.y + v3.y);
        } else {
            float v0 = __half2float(g[(size_t)s0 * FO + lane]);
            float v1 = __half2float(g[(size_t)s1 * FO + lane]);
            float v2 = __half2float(g[(size_t)s2 * FO + lane]);
            float v3 = __half2float(g[(size_t)s3 * FO + lane]);
            a0 += (v0 + v1) + (v2 + v3);
        }
    }
    for (; j < dg; ++j) {
        int s0 = csr[start + j];
        if (PER == 2) {
            float2 v0 = __half22float2(*(const __half2*)(g + (size_t)s0 * FO + lane * 2));
            a0 += v0.x; a1 += v0.y;
        } else {
            a0 += __half2float(g[(size_t)s0 * FO + lane]);
        }
    }

    float dn = dinv[node];
    if (PER == 2) {
        float2 bb = *(const float2*)(bias + lane * 2);
        float ox = fmaf(dn, a0, bb.x);
        float oy = fmaf(dn, a1, bb.y);
        if (RELU) { ox = fmaxf(ox, 0.f); oy = fmaxf(oy, 0.f); }
        if constexpr (sizeof(OT) == 2) {
            *(__half2*)((__half*)out + (size_t)node * FO + lane * 2) = __floats2half2_rn(ox, oy);
        } else {
            *(float2*)((float*)out + (size_t)node * FO + lane * 2) = make_float2(ox, oy);
        }
    } else {
        float o = fmaf(dn, a0, bias[lane]);
        if (RELU) o = fmaxf(o, 0.f);
        if constexpr (sizeof(OT) == 2) {
            ((__half*)out)[(size_t)node * FO + lane] = __float2half_rn(o);
        } else {
            ((float*)out)[(size_t)node * FO + lane] = o;
        }
    }
}

// ---------------- launch ----------------

extern "C" void kernel_launch(void* const* d_in, const int* in_sizes, int n_in,
                              void* d_out, int out_size, void* d_ws, size_t ws_size,
                              hipStream_t stream) {
    const float* x  = (const float*)d_in[0];
    const int*   ei = (const int*)d_in[1];    // harness passes integer inputs as int32
    const float* W0 = (const float*)d_in[2];
    const float* b0 = (const float*)d_in[3];
    const float* W1 = (const float*)d_in[4];
    const float* b1 = (const float*)d_in[5];
    const float* W2 = (const float*)d_in[6];
    const float* b2 = (const float*)d_in[7];
    float* out = (float*)d_out;

    const int N = in_sizes[0] / F_IN;
    const int E = in_sizes[1] / 2;
    const int* src = ei;
    const int* dst = ei + E;

    char* ws = (char*)d_ws;
    size_t off = 0;
    __half* bufA  = (__half*)(ws + off); off += (size_t)N * 128 * 2;  // g (fp16)
    __half* bufB  = (__half*)(ws + off); off += (size_t)N * 128 * 2;  // features (fp16)
    float* dinv   = (float*)(ws + off); off += (size_t)N * 4;
    int*   deg    = (int*)  (ws + off); off += (size_t)N * 4;
    int*   rowptr = (int*)  (ws + off); off += (size_t)N * 4;
    int*   cursor = (int*)  (ws + off); off += (size_t)N * 4;
    int*   bsum   = (int*)  (ws + off); off += 256 * 4;
    unsigned short* csr = (unsigned short*)(ws + off); off += (size_t)E * 2;
    off = (off + 255) & ~(size_t)255;
    __half* wt0 = (__half*)(ws + off); off += 128 * 128 * 2;
    __half* wt1 = (__half*)(ws + off); off += 128 * 128 * 2;
    __half* wt2 = (__half*)(ws + off); off += 64 * 128 * 2;

    const int nb_nodes = (N + 255) / 256;   // 196 blocks -> fits scan_bsum
    const int nb_edges = (E + 255) / 256;
    const int nb_aggr  = (N * 64 + 255) / 256;
    const int nb_gemm  = (N + 63) / 64;
    const int psize    = (N + NPART - 1) / NPART;

    prep_weights_kernel<<<160, 256, 0, stream>>>(W0, W1, W2, wt0, wt1, wt2);
    zero_int_kernel<<<nb_nodes, 256, 0, stream>>>(deg, N);
    deg_kernel<<<nb_edges, 256, 0, stream>>>(dst, deg, E);
    scan_blocks<<<nb_nodes, 256, 0, stream>>>(deg, rowptr, bsum, N);
    scan_bsum<<<1, 256, 0, stream>>>(bsum, nb_nodes);
    add_offsets_kernel<<<nb_nodes, 256, 0, stream>>>(rowptr, bsum, cursor, deg, dinv, N);
    build_csr_kernel<<<NPART * 128, 256, 0, stream>>>(src, dst, cursor, csr, E, psize);

    // ---- layer 0: x (fp32) -> bufA (g fp16) -> bufB (fp16) ----
    gemm_mfma_kernel<128, float><<<nb_gemm, 256, 0, stream>>>(x, wt0, dinv, bufA, N);
    aggregate_kernel<128, true, __half><<<nb_aggr, 256, 0, stream>>>(bufA, rowptr, deg, csr, dinv, b0, bufB, N);

    // ---- layer 1: bufB (fp16) -> bufA (g fp16) -> bufB (fp16) ----
    gemm_mfma_kernel<128, __half><<<nb_gemm, 256, 0, stream>>>(bufB, wt1, dinv, bufA, N);
    aggregate_kernel<128, true, __half><<<nb_aggr, 256, 0, stream>>>(bufA, rowptr, deg, csr, dinv, b1, bufB, N);

    // ---- layer 2: bufB (fp16) -> bufA (g fp16, N*64) -> out (fp32) ----
    gemm_mfma_kernel<64, __half><<<nb_gemm, 256, 0, stream>>>(bufB, wt2, dinv, bufA, N);
    aggregate_kernel<64, false, float><<<nb_aggr, 256, 0, stream>>>(bufA, rowptr, deg, csr, dinv, b2, out, N);
}

// Round 10
// 233.432 us; speedup vs baseline: 16.3946x; 1.0032x over previous
//
#include <hip/hip_runtime.h>
#include <hip/hip_fp16.h>

#define F_IN 128
#define NPART 8

struct alignas(16) half8 { __half2 h[4]; };
typedef _Float16 f16x8 __attribute__((ext_vector_type(8)));
typedef float f32x4 __attribute__((ext_vector_type(4)));

// ---------------- prep: transpose+convert weights to fp16 Wt[n][k] ----------------

__global__ void prep_weights_kernel(const float* __restrict__ W0, const float* __restrict__ W1,
                                    const float* __restrict__ W2, __half* __restrict__ Wt0,
                                    __half* __restrict__ Wt1, __half* __restrict__ Wt2) {
    int idx = blockIdx.x * 256 + threadIdx.x;   // 0..40959
    if (idx < 16384) {                          // W0: [128][128]
        int k = idx >> 7, n = idx & 127;
        Wt0[n * 128 + k] = __float2half_rn(W0[idx]);
    } else if (idx < 32768) {                   // W1: [128][128]
        int j = idx - 16384;
        int k = j >> 7, n = j & 127;
        Wt1[n * 128 + k] = __float2half_rn(W1[j]);
    } else if (idx < 40960) {                   // W2: [128][64]
        int j = idx - 32768;
        int k = j >> 6, n = j & 63;
        Wt2[n * 128 + k] = __float2half_rn(W2[j]);
    }
}

// ---------------- degree ----------------

__global__ void zero_int_kernel(int* __restrict__ p, int n) {
    int i = blockIdx.x * blockDim.x + threadIdx.x;
    if (i < n) p[i] = 0;
}

// dst-partitioned, XCD-affine degree count: partition p (blockIdx%NPART -> XCD p
// under round-robin dispatch) only counts dst in [lo,hi), so its 25KB deg slice
// stays XCD-L2-private -> no cross-XCD atomic line migration.
__global__ __launch_bounds__(256) void deg_part_kernel(
    const int* __restrict__ dst, int* __restrict__ deg, int E, int psize)
{
    const int part  = blockIdx.x % NPART;
    const int bslot = blockIdx.x / NPART;
    const int nb    = gridDim.x / NPART;
    const int lo = part * psize;
    const int hi = lo + psize;
    for (int e = bslot * 256 + threadIdx.x; e < E; e += nb * 256) {
        int d = dst[e];
        if (d >= lo && d < hi) atomicAdd(&deg[d], 1);
    }
}

// ---------------- CSR build: exclusive scan of deg + partitioned placement ----------------

__global__ void scan_blocks(const int* __restrict__ deg, int* __restrict__ rp,
                            int* __restrict__ bsum, int N) {
    __shared__ int tmp[256];
    int t = threadIdx.x, i = blockIdx.x * 256 + t;
    int v = (i < N) ? deg[i] : 0;
    tmp[t] = v;
    __syncthreads();
    for (int off = 1; off < 256; off <<= 1) {
        int a = (t >= off) ? tmp[t - off] : 0;
        __syncthreads();
        tmp[t] += a;
        __syncthreads();
    }
    if (i < N) rp[i] = tmp[t] - v;
    if (t == 255) bsum[blockIdx.x] = tmp[255];
}

__global__ void scan_bsum(int* __restrict__ bsum, int nb) {   // nb <= 256
    __shared__ int tmp[256];
    int t = threadIdx.x;
    int v = (t < nb) ? bsum[t] : 0;
    tmp[t] = v;
    __syncthreads();
    for (int off = 1; off < 256; off <<= 1) {
        int a = (t >= off) ? tmp[t - off] : 0;
        __syncthreads();
        tmp[t] += a;
        __syncthreads();
    }
    if (t < nb) bsum[t] = tmp[t] - v;
}

// also computes dinv (fused; deg is final here)
__global__ void add_offsets_kernel(int* __restrict__ rp, const int* __restrict__ bsum,
                                   int* __restrict__ cursor, const int* __restrict__ deg,
                                   float* __restrict__ dinv, int N) {
    int i = blockIdx.x * 256 + threadIdx.x;
    if (i < N) {
        int r = rp[i] + bsum[blockIdx.x];
        rp[i] = r;
        cursor[i] = r;
        dinv[i] = rsqrtf((float)(deg[i] + 1));   // +1 self-loop; always > 0
    }
}

// dst-partitioned, XCD-affine CSR build (u16 payload).
__global__ __launch_bounds__(256) void build_csr_kernel(
    const int* __restrict__ src, const int* __restrict__ dst,
    int* __restrict__ cursor, unsigned short* __restrict__ csr_src,
    int E, int psize)
{
    const int part  = blockIdx.x % NPART;
    const int bslot = blockIdx.x / NPART;
    const int nb    = gridDim.x / NPART;
    const int lo = part * psize;
    const int hi = lo + psize;
    for (int e = bslot * 256 + threadIdx.x; e < E; e += nb * 256) {
        int d = dst[e];
        if (d >= lo && d < hi) {
            int pos = atomicAdd(&cursor[d], 1);
            csr_src[pos] = (unsigned short)src[e];
        }
    }
}

// ---------------- MFMA GEMM: g = fp16(dinv * (X @ W)) ----------------
// BM=64 (4 waves x 16 rows), BN=128 or 64. A from global (row-major X),
// B = Wt[n][k] fp16 staged in LDS with +8-half row pad (16B-aligned, 2-way banks).
// Fragment maps: A: m=lane&15, k=ks*32+(lane>>4)*8+j ; B: n=lane&15, same k
// (identical k-map on both operands -> k-permutation cancels).
// C/D: col=lane&15, row=(lane>>4)*4+reg  [HW-verified m89/m91].

template<int BN, typename XT>
__global__ __launch_bounds__(256) void gemm_mfma_kernel(
    const XT* __restrict__ X, const __half* __restrict__ Wt,
    const float* __restrict__ dinv, __half* __restrict__ g, int N)
{
    constexpr int K  = 128;
    constexpr int KP = K + 8;
    constexpr int NT = BN / 16;
    __shared__ __half Ws[BN * KP];

    const int tid = threadIdx.x;
    for (int c = tid; c < BN * (K / 8); c += 256) {
        int n  = c >> 4;          // 16 chunks of 8 halves per row
        int k8 = c & 15;
        *(f16x8*)&Ws[n * KP + k8 * 8] =
            *(const f16x8*)((const _Float16*)Wt + n * K + k8 * 8);
    }
    __syncthreads();

    const int lane = tid & 63;
    const int w    = tid >> 6;
    const int lrow = lane & 15;
    const int kg   = lane >> 4;
    const int row0 = blockIdx.x * 64 + w * 16;
    const int gr   = row0 + lrow;

    f32x4 acc[NT];
    #pragma unroll
    for (int t = 0; t < NT; ++t) acc[t] = (f32x4){0.f, 0.f, 0.f, 0.f};

    #pragma unroll
    for (int ks = 0; ks < 4; ++ks) {
        const int k0 = ks * 32 + kg * 8;
        f16x8 a = {};
        if constexpr (sizeof(XT) == 4) {
            if (gr < N) {
                const float* p = (const float*)X + (size_t)gr * K + k0;
                float4 x0 = *(const float4*)p;
                float4 x1 = *(const float4*)(p + 4);
                a[0] = (_Float16)x0.x; a[1] = (_Float16)x0.y;
                a[2] = (_Float16)x0.z; a[3] = (_Float16)x0.w;
                a[4] = (_Float16)x1.x; a[5] = (_Float16)x1.y;
                a[6] = (_Float16)x1.z; a[7] = (_Float16)x1.w;
            }
        } else {
            if (gr < N)
                a = *(const f16x8*)((const _Float16*)X + (size_t)gr * K + k0);
        }
        #pragma unroll
        for (int t = 0; t < NT; ++t) {
            f16x8 b = *(const f16x8*)&Ws[(t * 16 + lrow) * KP + k0];
            acc[t] = __builtin_amdgcn_mfma_f32_16x16x32_f16(a, b, acc[t], 0, 0, 0);
        }
    }

    #pragma unroll
    for (int r = 0; r < 4; ++r) {
        int m = row0 + kg * 4 + r;
        if (m < N) {
            float dn = dinv[m];
            #pragma unroll
            for (int t = 0; t < NT; ++t)
                g[(size_t)m * BN + t * 16 + lrow] = __float2half_rn(dn * acc[t][r]);
        }
    }
}

// ---------------- CSR aggregation + finalize ----------------
// One 64-lane wave per dst node, fp16 gathers, fp32 accumulate, OT output.

template<int FO, bool RELU, typename OT>
__global__ __launch_bounds__(256) void aggregate_kernel(
    const __half* __restrict__ g, const int* __restrict__ rp, const int* __restrict__ deg,
    const unsigned short* __restrict__ csr, const float* __restrict__ dinv,
    const float* __restrict__ bias, OT* __restrict__ out, int N)
{
    constexpr int PER = FO / 64;   // 2 (FO=128) or 1 (FO=64)
    int gid  = blockIdx.x * 256 + threadIdx.x;
    int node = gid >> 6;
    int lane = gid & 63;
    if (node >= N) return;

    int start = rp[node];
    int dg    = deg[node];

    float a0 = 0.f, a1 = 0.f;
    if (PER == 2) {
        float2 sv = __half22float2(*(const __half2*)(g + (size_t)node * FO + lane * 2));
        a0 = sv.x; a1 = sv.y;                      // self-loop term
    } else {
        a0 = __half2float(g[(size_t)node * FO + lane]);
    }

    int j = 0;
    for (; j + 3 < dg; j += 4) {
        int s0 = csr[start + j];
        int s1 = csr[start + j + 1];
        int s2 = csr[start + j + 2];
        int s3 = csr[start + j + 3];
        if (PER == 2) {
            float2 v0 = __half22float2(*(const __half2*)(g + (size_t)s0 * FO + lane * 2));
            float2 v1 = __half22float2(*(const __half2*)(g + (size_t)s1 * FO + lane * 2));
            float2 v2 = __half22float2(*(const __half2*)(g + (size_t)s2 * FO + lane * 2));
            float2 v3 = __half22float2(*(const __half2*)(g + (size_t)s3 * FO + lane * 2));
            a0 += (v0.x + v1.x) + (v2.x + v3.x);
            a1 += (v0.y + v1.y) + (v2.y + v3.y);
        } else {
            float v0 = __half2float(g[(size_t)s0 * FO + lane]);
            float v1 = __half2float(g[(size_t)s1 * FO + lane]);
            float v2 = __half2float(g[(size_t)s2 * FO + lane]);
            float v3 = __half2float(g[(size_t)s3 * FO + lane]);
            a0 += (v0 + v1) + (v2 + v3);
        }
    }
    for (; j < dg; ++j) {
        int s0 = csr[start + j];
        if (PER == 2) {
            float2 v0 = __half22float2(*(const __half2*)(g + (size_t)s0 * FO + lane * 2));
            a0 += v0.x; a1 += v0.y;
        } else {
            a0 += __half2float(g[(size_t)s0 * FO + lane]);
        }
    }

    float dn = dinv[node];
    if (PER == 2) {
        float2 bb = *(const float2*)(bias + lane * 2);
        float ox = fmaf(dn, a0, bb.x);
        float oy = fmaf(dn, a1, bb.y);
        if (RELU) { ox = fmaxf(ox, 0.f); oy = fmaxf(oy, 0.f); }
        if constexpr (sizeof(OT) == 2) {
            *(__half2*)((__half*)out + (size_t)node * FO + lane * 2) = __floats2half2_rn(ox, oy);
        } else {
            *(float2*)((float*)out + (size_t)node * FO + lane * 2) = make_float2(ox, oy);
        }
    } else {
        float o = fmaf(dn, a0, bias[lane]);
        if (RELU) o = fmaxf(o, 0.f);
        if constexpr (sizeof(OT) == 2) {
            ((__half*)out)[(size_t)node * FO + lane] = __float2half_rn(o);
        } else {
            ((float*)out)[(size_t)node * FO + lane] = o;
        }
    }
}

// ---------------- launch ----------------

extern "C" void kernel_launch(void* const* d_in, const int* in_sizes, int n_in,
                              void* d_out, int out_size, void* d_ws, size_t ws_size,
                              hipStream_t stream) {
    const float* x  = (const float*)d_in[0];
    const int*   ei = (const int*)d_in[1];    // harness passes integer inputs as int32
    const float* W0 = (const float*)d_in[2];
    const float* b0 = (const float*)d_in[3];
    const float* W1 = (const float*)d_in[4];
    const float* b1 = (const float*)d_in[5];
    const float* W2 = (const float*)d_in[6];
    const float* b2 = (const float*)d_in[7];
    float* out = (float*)d_out;

    const int N = in_sizes[0] / F_IN;
    const int E = in_sizes[1] / 2;
    const int* src = ei;
    const int* dst = ei + E;

    char* ws = (char*)d_ws;
    size_t off = 0;
    __half* bufA  = (__half*)(ws + off); off += (size_t)N * 128 * 2;  // g (fp16)
    __half* bufB  = (__half*)(ws + off); off += (size_t)N * 128 * 2;  // features (fp16)
    float* dinv   = (float*)(ws + off); off += (size_t)N * 4;
    int*   deg    = (int*)  (ws + off); off += (size_t)N * 4;
    int*   rowptr = (int*)  (ws + off); off += (size_t)N * 4;
    int*   cursor = (int*)  (ws + off); off += (size_t)N * 4;
    int*   bsum   = (int*)  (ws + off); off += 256 * 4;
    unsigned short* csr = (unsigned short*)(ws + off); off += (size_t)E * 2;
    off = (off + 255) & ~(size_t)255;
    __half* wt0 = (__half*)(ws + off); off += 128 * 128 * 2;
    __half* wt1 = (__half*)(ws + off); off += 128 * 128 * 2;
    __half* wt2 = (__half*)(ws + off); off += 64 * 128 * 2;

    const int nb_nodes = (N + 255) / 256;   // 196 blocks -> fits scan_bsum
    const int nb_aggr  = (N * 64 + 255) / 256;
    const int nb_gemm  = (N + 63) / 64;
    const int psize    = (N + NPART - 1) / NPART;

    prep_weights_kernel<<<160, 256, 0, stream>>>(W0, W1, W2, wt0, wt1, wt2);
    zero_int_kernel<<<nb_nodes, 256, 0, stream>>>(deg, N);
    deg_part_kernel<<<NPART * 128, 256, 0, stream>>>(dst, deg, E, psize);
    scan_blocks<<<nb_nodes, 256, 0, stream>>>(deg, rowptr, bsum, N);
    scan_bsum<<<1, 256, 0, stream>>>(bsum, nb_nodes);
    add_offsets_kernel<<<nb_nodes, 256, 0, stream>>>(rowptr, bsum, cursor, deg, dinv, N);
    build_csr_kernel<<<NPART * 128, 256, 0, stream>>>(src, dst, cursor, csr, E, psize);

    // ---- layer 0: x (fp32) -> bufA (g fp16) -> bufB (fp16) ----
    gemm_mfma_kernel<128, float><<<nb_gemm, 256, 0, stream>>>(x, wt0, dinv, bufA, N);
    aggregate_kernel<128, true, __half><<<nb_aggr, 256, 0, stream>>>(bufA, rowptr, deg, csr, dinv, b0, bufB, N);

    // ---- layer 1: bufB (fp16) -> bufA (g fp16) -> bufB (fp16) ----
    gemm_mfma_kernel<128, __half><<<nb_gemm, 256, 0, stream>>>(bufB, wt1, dinv, bufA, N);
    aggregate_kernel<128, true, __half><<<nb_aggr, 256, 0, stream>>>(bufA, rowptr, deg, csr, dinv, b1, bufB, N);

    // ---- layer 2: bufB (fp16) -> bufA (g fp16, N*64) -> out (fp32) ----
    gemm_mfma_kernel<64, __half><<<nb_gemm, 256, 0, stream>>>(bufB, wt2, dinv, bufA, N);
    aggregate_kernel<64, false, float><<<nb_aggr, 256, 0, stream>>>(bufA, rowptr, deg, csr, dinv, b2, out, N);
}

// Round 11
// 211.093 us; speedup vs baseline: 18.1296x; 1.1058x over previous
//
#include <hip/hip_runtime.h>
#include <hip/hip_fp16.h>
#include <type_traits>

#define F_IN 128
#define NPART 8

typedef _Float16 f16x8 __attribute__((ext_vector_type(8)));
typedef _Float16 f16x4 __attribute__((ext_vector_type(4)));
typedef _Float16 f16x2 __attribute__((ext_vector_type(2)));
typedef float f32x4 __attribute__((ext_vector_type(4)));

// ---------------- setup: weight transpose->fp16 + deg zero (fused) ----------------

__global__ void setup_kernel(const float* __restrict__ W0, const float* __restrict__ W1,
                             const float* __restrict__ W2, __half* __restrict__ Wt0,
                             __half* __restrict__ Wt1, __half* __restrict__ Wt2,
                             int* __restrict__ deg, int N) {
    int idx = blockIdx.x * 256 + threadIdx.x;
    if (idx < 16384) {                          // W0: [128][128]
        int k = idx >> 7, n = idx & 127;
        Wt0[n * 128 + k] = __float2half_rn(W0[idx]);
    } else if (idx < 32768) {                   // W1: [128][128]
        int j = idx - 16384;
        int k = j >> 7, n = j & 127;
        Wt1[n * 128 + k] = __float2half_rn(W1[j]);
    } else if (idx < 40960) {                   // W2: [128][64]
        int j = idx - 32768;
        int k = j >> 6, n = j & 63;
        Wt2[n * 128 + k] = __float2half_rn(W2[j]);
    }
    if (idx < N) deg[idx] = 0;                  // grid sized to cover max(40960, N)
}

// ---------------- degree (dst-partitioned) ----------------

__global__ __launch_bounds__(256) void deg_part_kernel(
    const int* __restrict__ dst, int* __restrict__ deg, int E, int psize)
{
    const int part  = blockIdx.x % NPART;
    const int bslot = blockIdx.x / NPART;
    const int nb    = gridDim.x / NPART;
    const int lo = part * psize;
    const int hi = lo + psize;
    for (int e = bslot * 256 + threadIdx.x; e < E; e += nb * 256) {
        int d = dst[e];
        if (d >= lo && d < hi) atomicAdd(&deg[d], 1);
    }
}

// ---------------- CSR build: exclusive scan of deg + partitioned placement ----------------

__global__ void scan_blocks(const int* __restrict__ deg, int* __restrict__ rp,
                            int* __restrict__ bsum, int N) {
    __shared__ int tmp[256];
    int t = threadIdx.x, i = blockIdx.x * 256 + t;
    int v = (i < N) ? deg[i] : 0;
    tmp[t] = v;
    __syncthreads();
    for (int off = 1; off < 256; off <<= 1) {
        int a = (t >= off) ? tmp[t - off] : 0;
        __syncthreads();
        tmp[t] += a;
        __syncthreads();
    }
    if (i < N) rp[i] = tmp[t] - v;
    if (t == 255) bsum[blockIdx.x] = tmp[255];
}

__global__ void scan_bsum(int* __restrict__ bsum, int nb) {   // nb <= 256
    __shared__ int tmp[256];
    int t = threadIdx.x;
    int v = (t < nb) ? bsum[t] : 0;
    tmp[t] = v;
    __syncthreads();
    for (int off = 1; off < 256; off <<= 1) {
        int a = (t >= off) ? tmp[t - off] : 0;
        __syncthreads();
        tmp[t] += a;
        __syncthreads();
    }
    if (t < nb) bsum[t] = tmp[t] - v;
}

// also computes dinv (fused; deg is final here)
__global__ void add_offsets_kernel(int* __restrict__ rp, const int* __restrict__ bsum,
                                   int* __restrict__ cursor, const int* __restrict__ deg,
                                   float* __restrict__ dinv, int N) {
    int i = blockIdx.x * 256 + threadIdx.x;
    if (i < N) {
        int r = rp[i] + bsum[blockIdx.x];
        rp[i] = r;
        cursor[i] = r;
        dinv[i] = rsqrtf((float)(deg[i] + 1));   // +1 self-loop; always > 0
    }
}

// dst-partitioned CSR build (u16 payload).
__global__ __launch_bounds__(256) void build_csr_kernel(
    const int* __restrict__ src, const int* __restrict__ dst,
    int* __restrict__ cursor, unsigned short* __restrict__ csr_src,
    int E, int psize)
{
    const int part  = blockIdx.x % NPART;
    const int bslot = blockIdx.x / NPART;
    const int nb    = gridDim.x / NPART;
    const int lo = part * psize;
    const int hi = lo + psize;
    for (int e = bslot * 256 + threadIdx.x; e < E; e += nb * 256) {
        int d = dst[e];
        if (d >= lo && d < hi) {
            int pos = atomicAdd(&cursor[d], 1);
            csr_src[pos] = (unsigned short)src[e];
        }
    }
}

// ---------------- MFMA GEMM: g = fp16(dinv * (X @ W)) ----------------
// BM=64 (4 waves x 16 rows), BN=128 or 64. A from global (row-major X),
// B = Wt[n][k] fp16 staged in LDS with +8-half row pad.
// Fragment maps: A: m=lane&15, k=ks*32+(lane>>4)*8+j ; B: n=lane&15, same k.
// C/D: col=lane&15, row=(lane>>4)*4+reg  [HW-verified m89/m91].

template<int BN, typename XT>
__global__ __launch_bounds__(256) void gemm_mfma_kernel(
    const XT* __restrict__ X, const __half* __restrict__ Wt,
    const float* __restrict__ dinv, __half* __restrict__ g, int N)
{
    constexpr int K  = 128;
    constexpr int KP = K + 8;
    constexpr int NT = BN / 16;
    __shared__ __half Ws[BN * KP];

    const int tid = threadIdx.x;
    for (int c = tid; c < BN * (K / 8); c += 256) {
        int n  = c >> 4;
        int k8 = c & 15;
        *(f16x8*)&Ws[n * KP + k8 * 8] =
            *(const f16x8*)((const _Float16*)Wt + n * K + k8 * 8);
    }
    __syncthreads();

    const int lane = tid & 63;
    const int w    = tid >> 6;
    const int lrow = lane & 15;
    const int kg   = lane >> 4;
    const int row0 = blockIdx.x * 64 + w * 16;
    const int gr   = row0 + lrow;

    f32x4 acc[NT];
    #pragma unroll
    for (int t = 0; t < NT; ++t) acc[t] = (f32x4){0.f, 0.f, 0.f, 0.f};

    #pragma unroll
    for (int ks = 0; ks < 4; ++ks) {
        const int k0 = ks * 32 + kg * 8;
        f16x8 a = {};
        if constexpr (sizeof(XT) == 4) {
            if (gr < N) {
                const float* p = (const float*)X + (size_t)gr * K + k0;
                float4 x0 = *(const float4*)p;
                float4 x1 = *(const float4*)(p + 4);
                a[0] = (_Float16)x0.x; a[1] = (_Float16)x0.y;
                a[2] = (_Float16)x0.z; a[3] = (_Float16)x0.w;
                a[4] = (_Float16)x1.x; a[5] = (_Float16)x1.y;
                a[6] = (_Float16)x1.z; a[7] = (_Float16)x1.w;
            }
        } else {
            if (gr < N)
                a = *(const f16x8*)((const _Float16*)X + (size_t)gr * K + k0);
        }
        #pragma unroll
        for (int t = 0; t < NT; ++t) {
            f16x8 b = *(const f16x8*)&Ws[(t * 16 + lrow) * KP + k0];
            acc[t] = __builtin_amdgcn_mfma_f32_16x16x32_f16(a, b, acc[t], 0, 0, 0);
        }
    }

    #pragma unroll
    for (int r = 0; r < 4; ++r) {
        int m = row0 + kg * 4 + r;
        if (m < N) {
            float dn = dinv[m];
            #pragma unroll
            for (int t = 0; t < NT; ++t)
                g[(size_t)m * BN + t * 16 + lrow] = __float2half_rn(dn * acc[t][r]);
        }
    }
}

// ---------------- CSR aggregation + finalize ----------------
// 32 lanes per dst node (2 nodes/wave), 8B f16x4 gathers (FO=128) for 2x fewer
// load instrs and 2x in-flight gather bytes vs the 64-lane/4B layout.

template<int FO, bool RELU, typename OT>
__global__ __launch_bounds__(256) void aggregate_kernel(
    const __half* __restrict__ g, const int* __restrict__ rp, const int* __restrict__ deg,
    const unsigned short* __restrict__ csr, const float* __restrict__ dinv,
    const float* __restrict__ bias, OT* __restrict__ out, int N)
{
    constexpr int PER = FO / 32;   // 4 (FO=128) or 2 (FO=64)
    using VT = typename std::conditional<PER == 4, f16x4, f16x2>::type;

    int gid  = blockIdx.x * 256 + threadIdx.x;
    int node = gid >> 5;
    int lane = gid & 31;
    if (node >= N) return;

    int start = rp[node];
    int dg    = deg[node];

    const _Float16* gb = (const _Float16*)g + (size_t)lane * PER;

    float a[PER];
    {   // self-loop term
        VT v = *(const VT*)(gb + (size_t)node * FO);
        #pragma unroll
        for (int p = 0; p < PER; ++p) a[p] = (float)v[p];
    }

    int j = 0;
    for (; j + 3 < dg; j += 4) {
        int s0 = csr[start + j];
        int s1 = csr[start + j + 1];
        int s2 = csr[start + j + 2];
        int s3 = csr[start + j + 3];
        VT v0 = *(const VT*)(gb + (size_t)s0 * FO);
        VT v1 = *(const VT*)(gb + (size_t)s1 * FO);
        VT v2 = *(const VT*)(gb + (size_t)s2 * FO);
        VT v3 = *(const VT*)(gb + (size_t)s3 * FO);
        #pragma unroll
        for (int p = 0; p < PER; ++p)
            a[p] += ((float)v0[p] + (float)v1[p]) + ((float)v2[p] + (float)v3[p]);
    }
    for (; j < dg; ++j) {
        int s0 = csr[start + j];
        VT v0 = *(const VT*)(gb + (size_t)s0 * FO);
        #pragma unroll
        for (int p = 0; p < PER; ++p) a[p] += (float)v0[p];
    }

    float dn = dinv[node];
    float o[PER];
    #pragma unroll
    for (int p = 0; p < PER; ++p) {
        o[p] = fmaf(dn, a[p], bias[lane * PER + p]);
        if (RELU) o[p] = fmaxf(o[p], 0.f);
    }

    if constexpr (sizeof(OT) == 2) {
        VT h;
        #pragma unroll
        for (int p = 0; p < PER; ++p) h[p] = (_Float16)o[p];
        *(VT*)((_Float16*)out + (size_t)node * FO + lane * PER) = h;
    } else {
        float* op = (float*)out + (size_t)node * FO + lane * PER;
        if constexpr (PER == 4) {
            *(float4*)op = make_float4(o[0], o[1], o[2], o[3]);
        } else {
            *(float2*)op = make_float2(o[0], o[1]);
        }
    }
}

// ---------------- launch ----------------

extern "C" void kernel_launch(void* const* d_in, const int* in_sizes, int n_in,
                              void* d_out, int out_size, void* d_ws, size_t ws_size,
                              hipStream_t stream) {
    const float* x  = (const float*)d_in[0];
    const int*   ei = (const int*)d_in[1];    // harness passes integer inputs as int32
    const float* W0 = (const float*)d_in[2];
    const float* b0 = (const float*)d_in[3];
    const float* W1 = (const float*)d_in[4];
    const float* b1 = (const float*)d_in[5];
    const float* W2 = (const float*)d_in[6];
    const float* b2 = (const float*)d_in[7];
    float* out = (float*)d_out;

    const int N = in_sizes[0] / F_IN;
    const int E = in_sizes[1] / 2;
    const int* src = ei;
    const int* dst = ei + E;

    char* ws = (char*)d_ws;
    size_t off = 0;
    __half* bufA  = (__half*)(ws + off); off += (size_t)N * 128 * 2;  // g (fp16)
    __half* bufB  = (__half*)(ws + off); off += (size_t)N * 128 * 2;  // features (fp16)
    float* dinv   = (float*)(ws + off); off += (size_t)N * 4;
    int*   deg    = (int*)  (ws + off); off += (size_t)N * 4;
    int*   rowptr = (int*)  (ws + off); off += (size_t)N * 4;
    int*   cursor = (int*)  (ws + off); off += (size_t)N * 4;
    int*   bsum   = (int*)  (ws + off); off += 256 * 4;
    unsigned short* csr = (unsigned short*)(ws + off); off += (size_t)E * 2;
    off = (off + 255) & ~(size_t)255;
    __half* wt0 = (__half*)(ws + off); off += 128 * 128 * 2;
    __half* wt1 = (__half*)(ws + off); off += 128 * 128 * 2;
    __half* wt2 = (__half*)(ws + off); off += 64 * 128 * 2;

    const int nb_nodes = (N + 255) / 256;   // 196 blocks -> fits scan_bsum
    const int nb_setup = (((N > 40960 ? N : 40960) + 255) / 256);
    const int nb_aggr  = (N * 32 + 255) / 256;
    const int nb_gemm  = (N + 63) / 64;
    const int psize    = (N + NPART - 1) / NPART;

    setup_kernel<<<nb_setup, 256, 0, stream>>>(W0, W1, W2, wt0, wt1, wt2, deg, N);
    deg_part_kernel<<<NPART * 128, 256, 0, stream>>>(dst, deg, E, psize);
    scan_blocks<<<nb_nodes, 256, 0, stream>>>(deg, rowptr, bsum, N);
    scan_bsum<<<1, 256, 0, stream>>>(bsum, nb_nodes);
    add_offsets_kernel<<<nb_nodes, 256, 0, stream>>>(rowptr, bsum, cursor, deg, dinv, N);
    build_csr_kernel<<<NPART * 128, 256, 0, stream>>>(src, dst, cursor, csr, E, psize);

    // ---- layer 0: x (fp32) -> bufA (g fp16) -> bufB (fp16) ----
    gemm_mfma_kernel<128, float><<<nb_gemm, 256, 0, stream>>>(x, wt0, dinv, bufA, N);
    aggregate_kernel<128, true, __half><<<nb_aggr, 256, 0, stream>>>(bufA, rowptr, deg, csr, dinv, b0, bufB, N);

    // ---- layer 1: bufB (fp16) -> bufA (g fp16) -> bufB (fp16) ----
    gemm_mfma_kernel<128, __half><<<nb_gemm, 256, 0, stream>>>(bufB, wt1, dinv, bufA, N);
    aggregate_kernel<128, true, __half><<<nb_aggr, 256, 0, stream>>>(bufA, rowptr, deg, csr, dinv, b1, bufB, N);

    // ---- layer 2: bufB (fp16) -> bufA (g fp16, N*64) -> out (fp32) ----
    gemm_mfma_kernel<64, __half><<<nb_gemm, 256, 0, stream>>>(bufB, wt2, dinv, bufA, N);
    aggregate_kernel<64, false, float><<<nb_aggr, 256, 0, stream>>>(bufA, rowptr, deg, csr, dinv, b2, out, N);
}